// Round 8
// baseline (199.373 us; speedup 1.0000x reference)
//
#include <hip/hip_runtime.h>

#define SEQ 8
#define DIM 16
#define FF 32
#define VOCAB 256

// ds_swizzle XOR butterfly on a float (src_lane = lane ^ T, T<8 stays within
// the 8-lane item group). BitMode offset = (xor<<10) | (or<<5) | and, and=0x1F.
#define SWZF(val, imm) __int_as_float(__builtin_amdgcn_ds_swizzle(__float_as_int(val), (imm)))

// ---------------------------------------------------------------------------
// Body v5 = round-4 swizzle body with the weight stream moved to VMEM.
// Theory: R4's s_load weights (lgkmcnt) forced full-queue drains at every
// ds_swizzle consumption (SMEM is out-of-order vs DS on the shared lgkm
// counter) -> ~29 cyc/instr critical path. Forcing weights through
// global_load (vmcnt, deep queue, VGPR-buffered, L1-broadcast) decouples the
// weight stream from the swizzle chain entirely.
// The opaque `vz` (VGPR zero via inline asm) makes weight addresses
// per-lane so the compiler cannot scalarize them back to s_load.
// ---------------------------------------------------------------------------
__global__ __launch_bounds__(256, 4) void body_kernel(
    const int* __restrict__ x,
    const float* __restrict__ token_embed,
    const float* __restrict__ pos_embed,
    const float* __restrict__ Wq, const float* __restrict__ bq,
    const float* __restrict__ Wk, const float* __restrict__ bk,
    const float* __restrict__ Wv, const float* __restrict__ bv,
    const float* __restrict__ Wo, const float* __restrict__ bo,
    const float* __restrict__ W1, const float* __restrict__ b1,
    const float* __restrict__ W2, const float* __restrict__ b2,
    float* __restrict__ xout)
{
    const int tid = threadIdx.x;
    const int n = tid & 7;                                   // seq position
    const size_t row = (size_t)blockIdx.x * 256 + tid;       // global row id

    // Opaque zero in a VGPR: compiler cannot fold it, so weight addresses
    // become per-lane -> global_load (vmcnt) instead of s_load (lgkmcnt).
    int vz;
    asm volatile("v_mov_b32 %0, 0" : "=v"(vz));

    const float* Wqv = Wq + vz;
    const float* Wkv = Wk + vz;
    const float* Wvv = Wv + vz;
    const float* Wov = Wo + vz;
    const float* W1v = W1 + vz;
    const float* W2v = W2 + vz;

    // ---------------- embedding + positional ----------------
    float X[DIM];
    {
        const int idx = x[row];
        const float4* te = (const float4*)(token_embed + (size_t)idx * DIM);
        const float4* pe = (const float4*)(pos_embed + n * DIM);
        #pragma unroll
        for (int j = 0; j < 4; ++j) {
            float4 a = te[j];
            float4 p = pe[j];
            X[4*j+0] = a.x + p.x;
            X[4*j+1] = a.y + p.y;
            X[4*j+2] = a.z + p.z;
            X[4*j+3] = a.w + p.w;
        }
    }

    // ---------------- QKV: outer-product over d, 48 acc chains ----------------
    float q[DIM], k[DIM], v[DIM];
    {
        const float4* bq4 = (const float4*)(bq + vz);
        const float4* bk4 = (const float4*)(bk + vz);
        const float4* bv4 = (const float4*)(bv + vz);
        #pragma unroll
        for (int j = 0; j < 4; ++j) {
            float4 a = bq4[j], b = bk4[j], c = bv4[j];
            q[4*j+0] = a.x; q[4*j+1] = a.y; q[4*j+2] = a.z; q[4*j+3] = a.w;
            k[4*j+0] = b.x; k[4*j+1] = b.y; k[4*j+2] = b.z; k[4*j+3] = b.w;
            v[4*j+0] = c.x; v[4*j+1] = c.y; v[4*j+2] = c.z; v[4*j+3] = c.w;
        }
    }
    #pragma unroll
    for (int d = 0; d < DIM; ++d) {
        const float xd = X[d];
        #pragma unroll
        for (int jj = 0; jj < 4; ++jj) {
            float4 wq = *(const float4*)(Wqv + d * DIM + 4 * jj);
            float4 wk = *(const float4*)(Wkv + d * DIM + 4 * jj);
            float4 wv = *(const float4*)(Wvv + d * DIM + 4 * jj);
            q[4*jj+0] += xd * wq.x; q[4*jj+1] += xd * wq.y;
            q[4*jj+2] += xd * wq.z; q[4*jj+3] += xd * wq.w;
            k[4*jj+0] += xd * wk.x; k[4*jj+1] += xd * wk.y;
            k[4*jj+2] += xd * wk.z; k[4*jj+3] += xd * wk.w;
            v[4*jj+0] += xd * wv.x; v[4*jj+1] += xd * wv.y;
            v[4*jj+2] += xd * wv.z; v[4*jj+3] += xd * wv.w;
        }
    }

    // ---------------- attention scores via XOR butterfly ----------------
    float sc[SEQ];
    {
        float s = 0.f;
        #pragma unroll
        for (int d = 0; d < DIM; ++d) s += q[d] * k[d];      // t = 0 (self)
        sc[0] = s * 0.25f;
    }
    #define SCORE_PHASE(T, IMM)                                   \
    {                                                             \
        float s = 0.f;                                            \
        _Pragma("unroll")                                         \
        for (int d = 0; d < DIM; ++d) s += q[d] * SWZF(k[d], IMM);\
        sc[T] = s * 0.25f;                                        \
    }
    SCORE_PHASE(1, 0x041F)
    SCORE_PHASE(2, 0x081F)
    SCORE_PHASE(3, 0x0C1F)
    SCORE_PHASE(4, 0x101F)
    SCORE_PHASE(5, 0x141F)
    SCORE_PHASE(6, 0x181F)
    SCORE_PHASE(7, 0x1C1F)
    #undef SCORE_PHASE

    // ---------------- softmax over the 8 scores (per-lane) ----------------
    float mx = sc[0];
    #pragma unroll
    for (int m = 1; m < SEQ; ++m) mx = fmaxf(mx, sc[m]);
    float sum = 0.f;
    float w[SEQ];
    #pragma unroll
    for (int m = 0; m < SEQ; ++m) { w[m] = __expf(sc[m] - mx); sum += w[m]; }
    const float inv = 1.0f / sum;
    #pragma unroll
    for (int m = 0; m < SEQ; ++m) w[m] *= inv;

    // ---------------- PV via XOR butterfly ----------------
    float at[DIM];
    #pragma unroll
    for (int d = 0; d < DIM; ++d) at[d] = w[0] * v[d];       // t = 0 (self)
    #define PV_PHASE(T, IMM)                                      \
    {                                                             \
        const float wt = w[T];                                    \
        _Pragma("unroll")                                         \
        for (int d = 0; d < DIM; ++d) at[d] += wt * SWZF(v[d], IMM);\
    }
    PV_PHASE(1, 0x041F)
    PV_PHASE(2, 0x081F)
    PV_PHASE(3, 0x0C1F)
    PV_PHASE(4, 0x101F)
    PV_PHASE(5, 0x141F)
    PV_PHASE(6, 0x181F)
    PV_PHASE(7, 0x1C1F)
    #undef PV_PHASE

    // ---------------- O projection + residual ----------------
    float X1[DIM];
    {
        const float4* bo4 = (const float4*)(bo + vz);
        #pragma unroll
        for (int j = 0; j < 4; ++j) {
            float4 b = bo4[j];
            X1[4*j+0] = X[4*j+0] + b.x;
            X1[4*j+1] = X[4*j+1] + b.y;
            X1[4*j+2] = X[4*j+2] + b.z;
            X1[4*j+3] = X[4*j+3] + b.w;
        }
    }
    #pragma unroll
    for (int d = 0; d < DIM; ++d) {
        const float ad = at[d];
        #pragma unroll
        for (int jj = 0; jj < 4; ++jj) {
            float4 wo = *(const float4*)(Wov + d * DIM + 4 * jj);
            X1[4*jj+0] += ad * wo.x;
            X1[4*jj+1] += ad * wo.y;
            X1[4*jj+2] += ad * wo.z;
            X1[4*jj+3] += ad * wo.w;
        }
    }

    // ---------------- FFN + residual ----------------
    float h[FF];
    {
        const float4* b14 = (const float4*)(b1 + vz);
        #pragma unroll
        for (int j = 0; j < 8; ++j) {
            float4 b = b14[j];
            h[4*j+0] = b.x; h[4*j+1] = b.y; h[4*j+2] = b.z; h[4*j+3] = b.w;
        }
    }
    #pragma unroll
    for (int d = 0; d < DIM; ++d) {
        const float xd = X1[d];
        #pragma unroll
        for (int jj = 0; jj < 8; ++jj) {
            float4 w1 = *(const float4*)(W1v + d * FF + 4 * jj);
            h[4*jj+0] += xd * w1.x;
            h[4*jj+1] += xd * w1.y;
            h[4*jj+2] += xd * w1.z;
            h[4*jj+3] += xd * w1.w;
        }
    }
    #pragma unroll
    for (int f = 0; f < FF; ++f) h[f] = fmaxf(h[f], 0.f);

    float X2[DIM];
    {
        const float4* b24 = (const float4*)(b2 + vz);
        #pragma unroll
        for (int j = 0; j < 4; ++j) {
            float4 b = b24[j];
            X2[4*j+0] = X1[4*j+0] + b.x;
            X2[4*j+1] = X1[4*j+1] + b.y;
            X2[4*j+2] = X1[4*j+2] + b.z;
            X2[4*j+3] = X1[4*j+3] + b.w;
        }
    }
    #pragma unroll
    for (int f = 0; f < FF; ++f) {
        const float hf = h[f];
        #pragma unroll
        for (int jj = 0; jj < 4; ++jj) {
            float4 w2 = *(const float4*)(W2v + f * DIM + 4 * jj);
            X2[4*jj+0] += hf * w2.x;
            X2[4*jj+1] += hf * w2.y;
            X2[4*jj+2] += hf * w2.z;
            X2[4*jj+3] += hf * w2.w;
        }
    }

    // ---------------- write X2 row ----------------
    float4* dst = (float4*)(xout + row * DIM);
    #pragma unroll
    for (int j = 0; j < 4; ++j) {
        float4 xx;
        xx.x = X2[4*j+0]; xx.y = X2[4*j+1]; xx.z = X2[4*j+2]; xx.w = X2[4*j+3];
        dst[j] = xx;
    }
}

// ---------------------------------------------------------------------------
// Head v1 (proven ~49us): vocab GEMM [R,16] @ [16,256] + bias. 1 col/lane,
// 16 weight VGPRs, wave-uniform s_load of each X row, coalesced stores.
// 8192 blocks = 32768 waves -> 8 waves/SIMD.
// ---------------------------------------------------------------------------
#define ROWS_PER_BLOCK 32

__global__ __launch_bounds__(256) void head_kernel(
    const float* __restrict__ xin,
    const float* __restrict__ Wh,
    const float* __restrict__ bh,
    float* __restrict__ out)
{
    const int tid = threadIdx.x;
    const int col = tid;
    float wh[DIM];
    #pragma unroll
    for (int d = 0; d < DIM; ++d) wh[d] = Wh[d * VOCAB + col];
    const float bhv = bh[col];

    const size_t row0 = (size_t)blockIdx.x * ROWS_PER_BLOCK;
    #pragma unroll 4
    for (int r = 0; r < ROWS_PER_BLOCK; ++r) {
        const float* xr = xin + (row0 + r) * DIM;  // wave-uniform address
        float acc = bhv;
        #pragma unroll
        for (int d = 0; d < DIM; ++d) acc += xr[d] * wh[d];
        out[(row0 + r) * VOCAB + col] = acc;
    }
}

// ---------------------------------------------------------------------------
// Fallback (ws too small): single-pass per-row body + per-column head.
// ---------------------------------------------------------------------------
#define ITEMS_PER_BLOCK 32
#define ITEM_STRIDE 136

__global__ __launch_bounds__(256) void fused_fallback_kernel(
    const int* __restrict__ x,
    const float* __restrict__ token_embed,
    const float* __restrict__ pos_embed,
    const float* __restrict__ Wq, const float* __restrict__ bq,
    const float* __restrict__ Wk, const float* __restrict__ bk,
    const float* __restrict__ Wv, const float* __restrict__ bv,
    const float* __restrict__ Wo, const float* __restrict__ bo,
    const float* __restrict__ W1, const float* __restrict__ b1,
    const float* __restrict__ W2, const float* __restrict__ b2,
    const float* __restrict__ Wh, const float* __restrict__ bh,
    float* __restrict__ out)
{
    __shared__ float sK[ITEMS_PER_BLOCK * ITEM_STRIDE];
    __shared__ float sV[ITEMS_PER_BLOCK * ITEM_STRIDE];

    const int tid = threadIdx.x;
    const int i = tid >> 3;
    const int n = tid & 7;
    const int b = blockIdx.x * ITEMS_PER_BLOCK + i;

    float X[DIM];
    {
        const int idx = x[b * SEQ + n];
        const float4* te = (const float4*)(token_embed + idx * DIM);
        const float4* pe = (const float4*)(pos_embed + n * DIM);
        #pragma unroll
        for (int j = 0; j < 4; ++j) {
            float4 a = te[j];
            float4 p = pe[j];
            X[4*j+0] = a.x + p.x; X[4*j+1] = a.y + p.y;
            X[4*j+2] = a.z + p.z; X[4*j+3] = a.w + p.w;
        }
    }

    float Q[DIM], Kr[DIM], Vr[DIM];
    #pragma unroll
    for (int e = 0; e < DIM; ++e) {
        float qq = bq[e], kk = bk[e], vv = bv[e];
        #pragma unroll
        for (int d = 0; d < DIM; ++d) {
            qq += X[d] * Wq[d * DIM + e];
            kk += X[d] * Wk[d * DIM + e];
            vv += X[d] * Wv[d * DIM + e];
        }
        Q[e] = qq; Kr[e] = kk; Vr[e] = vv;
    }
    {
        float* kdst = sK + i * ITEM_STRIDE + n * DIM;
        float* vdst = sV + i * ITEM_STRIDE + n * DIM;
        #pragma unroll
        for (int j = 0; j < 4; ++j) {
            float4 kk, vv;
            kk.x = Kr[4*j+0]; kk.y = Kr[4*j+1]; kk.z = Kr[4*j+2]; kk.w = Kr[4*j+3];
            vv.x = Vr[4*j+0]; vv.y = Vr[4*j+1]; vv.z = Vr[4*j+2]; vv.w = Vr[4*j+3];
            ((float4*)kdst)[j] = kk;
            ((float4*)vdst)[j] = vv;
        }
    }
    __syncthreads();

    float sc[SEQ];
    #pragma unroll
    for (int m = 0; m < SEQ; ++m) {
        const float* kr = sK + i * ITEM_STRIDE + m * DIM;
        float s = 0.f;
        #pragma unroll
        for (int d = 0; d < DIM; ++d) s += Q[d] * kr[d];
        sc[m] = s * 0.25f;
    }
    float mx = sc[0];
    #pragma unroll
    for (int m = 1; m < SEQ; ++m) mx = fmaxf(mx, sc[m]);
    float sum = 0.f;
    #pragma unroll
    for (int m = 0; m < SEQ; ++m) { sc[m] = __expf(sc[m] - mx); sum += sc[m]; }
    const float inv = 1.0f / sum;

    float at[DIM];
    #pragma unroll
    for (int d = 0; d < DIM; ++d) at[d] = 0.f;
    #pragma unroll
    for (int m = 0; m < SEQ; ++m) {
        const float w = sc[m] * inv;
        const float* vr = sV + i * ITEM_STRIDE + m * DIM;
        #pragma unroll
        for (int d = 0; d < DIM; ++d) at[d] += w * vr[d];
    }

    float X1[DIM];
    #pragma unroll
    for (int e = 0; e < DIM; ++e) {
        float o = bo[e];
        #pragma unroll
        for (int d = 0; d < DIM; ++d) o += at[d] * Wo[d * DIM + e];
        X1[e] = X[e] + o;
    }
    float h[FF];
    #pragma unroll
    for (int f = 0; f < FF; ++f) {
        float a = b1[f];
        #pragma unroll
        for (int d = 0; d < DIM; ++d) a += X1[d] * W1[d * FF + f];
        h[f] = fmaxf(a, 0.f);
    }
    float X2[DIM];
    #pragma unroll
    for (int e = 0; e < DIM; ++e) {
        float a = b2[e];
        #pragma unroll
        for (int f = 0; f < FF; ++f) a += h[f] * W2[f * DIM + e];
        X2[e] = X1[e] + a;
    }

    __syncthreads();
    {
        float* xdst = sK + i * ITEM_STRIDE + n * DIM;
        #pragma unroll
        for (int j = 0; j < 4; ++j) {
            float4 xx;
            xx.x = X2[4*j+0]; xx.y = X2[4*j+1]; xx.z = X2[4*j+2]; xx.w = X2[4*j+3];
            ((float4*)xdst)[j] = xx;
        }
    }
    __syncthreads();

    float wh[DIM];
    #pragma unroll
    for (int d = 0; d < DIM; ++d) wh[d] = Wh[d * VOCAB + tid];
    const float bhv = bh[tid];

    const size_t obase = (size_t)blockIdx.x * (ITEMS_PER_BLOCK * SEQ) * VOCAB + tid;
    #pragma unroll 4
    for (int r = 0; r < ITEMS_PER_BLOCK * SEQ; ++r) {
        const float* xr = sK + (r >> 3) * ITEM_STRIDE + (r & 7) * DIM;
        float acc = bhv;
        #pragma unroll
        for (int d = 0; d < DIM; ++d) acc += xr[d] * wh[d];
        out[obase + (size_t)r * VOCAB] = acc;
    }
}

extern "C" void kernel_launch(void* const* d_in, const int* in_sizes, int n_in,
                              void* d_out, int out_size, void* d_ws, size_t ws_size,
                              hipStream_t stream) {
    const int*   x           = (const int*)  d_in[0];
    const float* token_embed = (const float*)d_in[1];
    const float* pos_embed   = (const float*)d_in[2];
    const float* Wq = (const float*)d_in[3];
    const float* bq = (const float*)d_in[4];
    const float* Wk = (const float*)d_in[5];
    const float* bk = (const float*)d_in[6];
    const float* Wv = (const float*)d_in[7];
    const float* bv = (const float*)d_in[8];
    const float* Wo = (const float*)d_in[9];
    const float* bo = (const float*)d_in[10];
    const float* W1 = (const float*)d_in[11];
    const float* b1 = (const float*)d_in[12];
    const float* W2 = (const float*)d_in[13];
    const float* b2 = (const float*)d_in[14];
    const float* Wh = (const float*)d_in[15];
    const float* bh = (const float*)d_in[16];
    float* out = (float*)d_out;

    const int B = in_sizes[0] / SEQ;                 // 32768
    const int nrows = B * SEQ;                       // 262144
    const size_t ws_needed = (size_t)nrows * DIM * sizeof(float);  // 16 MB

    if (ws_size >= ws_needed) {
        float* xws = (float*)d_ws;
        body_kernel<<<nrows / 256, 256, 0, stream>>>(
            x, token_embed, pos_embed, Wq, bq, Wk, bk, Wv, bv, Wo, bo,
            W1, b1, W2, b2, xws);
        head_kernel<<<nrows / ROWS_PER_BLOCK, 256, 0, stream>>>(
            xws, Wh, bh, out);
    } else {
        fused_fallback_kernel<<<B / ITEMS_PER_BLOCK, 256, 0, stream>>>(
            x, token_embed, pos_embed, Wq, bq, Wk, bk, Wv, bv, Wo, bo,
            W1, b1, W2, b2, Wh, bh, out);
    }
}

// Round 9
// 153.692 us; speedup vs baseline: 1.2972x; 1.2972x over previous
//
#include <hip/hip_runtime.h>
#include <stdint.h>

#define SEQ 8
#define DIM 16
#define FF 32
#define VOCAB 256

// ds_swizzle XOR butterfly on a float (src_lane = lane ^ T, T<8 stays within
// the 8-lane item group). BitMode offset = (xor<<10) | (or<<5) | and, and=0x1F.
#define SWZF(val, imm) __int_as_float(__builtin_amdgcn_ds_swizzle(__float_as_int(val), (imm)))

// Packed-weight dword layout in d_ws (after the 16MB X2 buffer), pair = 2 bf16:
// pWq 0, pWk 128, pWv 256, pWo 384, pW1 512 (256), pW2 768 (256) -> 1024 dwords
#define PW_WQ 0
#define PW_WK 128
#define PW_WV 256
#define PW_WO 384
#define PW_W1 512
#define PW_W2 768
#define PW_TOT 1024

__device__ __forceinline__ uint32_t bf16_rne(float f) {
    uint32_t u = __float_as_uint(f);
    return (u + 0x7fffu + ((u >> 16) & 1u)) >> 16;   // round-to-nearest-even
}

// ---------------------------------------------------------------------------
// Pre-pass: pack the 6 weight matrices into bf16 pairs (1024 dwords, 4KB).
// ---------------------------------------------------------------------------
__global__ __launch_bounds__(256) void pack_weights_kernel(
    const float* __restrict__ Wq, const float* __restrict__ Wk,
    const float* __restrict__ Wv, const float* __restrict__ Wo,
    const float* __restrict__ W1, const float* __restrict__ W2,
    uint32_t* __restrict__ pw)
{
    const int i = blockIdx.x * 256 + threadIdx.x;   // 0..1023
    if (i >= PW_TOT) return;
    const float* src; int off;
    if      (i < PW_WK) { src = Wq; off = i - PW_WQ; }
    else if (i < PW_WV) { src = Wk; off = i - PW_WK; }
    else if (i < PW_WO) { src = Wv; off = i - PW_WV; }
    else if (i < PW_W1) { src = Wo; off = i - PW_WO; }
    else if (i < PW_W2) { src = W1; off = i - PW_W1; }
    else                { src = W2; off = i - PW_W2; }
    const float a = src[2 * off];
    const float b = src[2 * off + 1];
    pw[i] = (bf16_rne(b) << 16) | bf16_rne(a);
}

// unpack pair -> two f32 (wave-uniform: compiler keeps these on the SALU)
#define UNPK(u, lo, hi)                                  \
    const float lo = __uint_as_float((u) << 16);         \
    const float hi = __uint_as_float((u) & 0xffff0000u);

// ---------------------------------------------------------------------------
// Body v6 = round-4 swizzle body (proven structure) with the s_load weight
// stream halved: weights arrive as bf16 pairs in uniform dwords; unpack is
// wave-uniform s_lshl/s_and (SALU pipe, otherwise idle), FMA src0 = SGPR.
// ---------------------------------------------------------------------------
__global__ __launch_bounds__(256, 4) void body_kernel(
    const int* __restrict__ x,
    const float* __restrict__ token_embed,
    const float* __restrict__ pos_embed,
    const uint32_t* __restrict__ pw,
    const float* __restrict__ bq, const float* __restrict__ bk,
    const float* __restrict__ bv, const float* __restrict__ bo,
    const float* __restrict__ b1, const float* __restrict__ b2,
    float* __restrict__ xout)
{
    const uint32_t* pWq = pw + PW_WQ;
    const uint32_t* pWk = pw + PW_WK;
    const uint32_t* pWv = pw + PW_WV;
    const uint32_t* pWo = pw + PW_WO;
    const uint32_t* pW1 = pw + PW_W1;
    const uint32_t* pW2 = pw + PW_W2;

    const int tid = threadIdx.x;
    const int n = tid & 7;                                   // seq position
    const size_t row = (size_t)blockIdx.x * 256 + tid;       // global row id

    // ---------------- embedding + positional ----------------
    float X[DIM];
    {
        const int idx = x[row];
        const float4* te = (const float4*)(token_embed + (size_t)idx * DIM);
        const float4* pe = (const float4*)(pos_embed + n * DIM);
        #pragma unroll
        for (int j = 0; j < 4; ++j) {
            float4 a = te[j];
            float4 p = pe[j];
            X[4*j+0] = a.x + p.x;
            X[4*j+1] = a.y + p.y;
            X[4*j+2] = a.z + p.z;
            X[4*j+3] = a.w + p.w;
        }
    }

    // ---------------- QKV: outer-product over d, 48 acc chains ----------------
    float q[DIM], k[DIM], v[DIM];
    #pragma unroll
    for (int e = 0; e < DIM; ++e) { q[e] = bq[e]; k[e] = bk[e]; v[e] = bv[e]; }
    #pragma unroll
    for (int d = 0; d < DIM; ++d) {
        const float xd = X[d];
        #pragma unroll
        for (int jj = 0; jj < 8; ++jj) {
            const uint32_t uq = pWq[d * 8 + jj];
            const uint32_t uk = pWk[d * 8 + jj];
            const uint32_t uv = pWv[d * 8 + jj];
            UNPK(uq, qlo, qhi)
            UNPK(uk, klo, khi)
            UNPK(uv, vlo, vhi)
            q[2*jj]   += xd * qlo;  q[2*jj+1] += xd * qhi;
            k[2*jj]   += xd * klo;  k[2*jj+1] += xd * khi;
            v[2*jj]   += xd * vlo;  v[2*jj+1] += xd * vhi;
        }
    }

    // ---------------- attention scores via XOR butterfly ----------------
    float sc[SEQ];
    {
        float s = 0.f;
        #pragma unroll
        for (int d = 0; d < DIM; ++d) s += q[d] * k[d];      // t = 0 (self)
        sc[0] = s * 0.25f;
    }
    #define SCORE_PHASE(T, IMM)                                   \
    {                                                             \
        float s = 0.f;                                            \
        _Pragma("unroll")                                         \
        for (int d = 0; d < DIM; ++d) s += q[d] * SWZF(k[d], IMM);\
        sc[T] = s * 0.25f;                                        \
    }
    SCORE_PHASE(1, 0x041F)
    SCORE_PHASE(2, 0x081F)
    SCORE_PHASE(3, 0x0C1F)
    SCORE_PHASE(4, 0x101F)
    SCORE_PHASE(5, 0x141F)
    SCORE_PHASE(6, 0x181F)
    SCORE_PHASE(7, 0x1C1F)
    #undef SCORE_PHASE

    // ---------------- softmax over the 8 scores (per-lane) ----------------
    float mx = sc[0];
    #pragma unroll
    for (int m = 1; m < SEQ; ++m) mx = fmaxf(mx, sc[m]);
    float sum = 0.f;
    float w[SEQ];
    #pragma unroll
    for (int m = 0; m < SEQ; ++m) { w[m] = __expf(sc[m] - mx); sum += w[m]; }
    const float inv = 1.0f / sum;
    #pragma unroll
    for (int m = 0; m < SEQ; ++m) w[m] *= inv;

    // ---------------- PV via XOR butterfly ----------------
    float at[DIM];
    #pragma unroll
    for (int d = 0; d < DIM; ++d) at[d] = w[0] * v[d];       // t = 0 (self)
    #define PV_PHASE(T, IMM)                                      \
    {                                                             \
        const float wt = w[T];                                    \
        _Pragma("unroll")                                         \
        for (int d = 0; d < DIM; ++d) at[d] += wt * SWZF(v[d], IMM);\
    }
    PV_PHASE(1, 0x041F)
    PV_PHASE(2, 0x081F)
    PV_PHASE(3, 0x0C1F)
    PV_PHASE(4, 0x101F)
    PV_PHASE(5, 0x141F)
    PV_PHASE(6, 0x181F)
    PV_PHASE(7, 0x1C1F)
    #undef PV_PHASE

    // ---------------- O projection + residual ----------------
    float X1[DIM];
    #pragma unroll
    for (int e = 0; e < DIM; ++e) X1[e] = X[e] + bo[e];
    #pragma unroll
    for (int d = 0; d < DIM; ++d) {
        const float ad = at[d];
        #pragma unroll
        for (int jj = 0; jj < 8; ++jj) {
            const uint32_t uo = pWo[d * 8 + jj];
            UNPK(uo, olo, ohi)
            X1[2*jj]   += ad * olo;
            X1[2*jj+1] += ad * ohi;
        }
    }

    // ---------------- FFN + residual ----------------
    float h[FF];
    #pragma unroll
    for (int f = 0; f < FF; ++f) h[f] = b1[f];
    #pragma unroll
    for (int d = 0; d < DIM; ++d) {
        const float xd = X1[d];
        #pragma unroll
        for (int jj = 0; jj < 16; ++jj) {
            const uint32_t u1 = pW1[d * 16 + jj];
            UNPK(u1, w1lo, w1hi)
            h[2*jj]   += xd * w1lo;
            h[2*jj+1] += xd * w1hi;
        }
    }
    #pragma unroll
    for (int f = 0; f < FF; ++f) h[f] = fmaxf(h[f], 0.f);

    float X2[DIM];
    #pragma unroll
    for (int e = 0; e < DIM; ++e) X2[e] = X1[e] + b2[e];
    #pragma unroll
    for (int f = 0; f < FF; ++f) {
        const float hf = h[f];
        #pragma unroll
        for (int jj = 0; jj < 8; ++jj) {
            const uint32_t u2 = pW2[f * 8 + jj];
            UNPK(u2, w2lo, w2hi)
            X2[2*jj]   += hf * w2lo;
            X2[2*jj+1] += hf * w2hi;
        }
    }

    // ---------------- write X2 row ----------------
    float4* dst = (float4*)(xout + row * DIM);
    #pragma unroll
    for (int j = 0; j < 4; ++j) {
        float4 xx;
        xx.x = X2[4*j+0]; xx.y = X2[4*j+1]; xx.z = X2[4*j+2]; xx.w = X2[4*j+3];
        dst[j] = xx;
    }
}

// ---------------------------------------------------------------------------
// Head v1 (proven ~49us): vocab GEMM [R,16] @ [16,256] + bias. 1 col/lane,
// 16 weight VGPRs, wave-uniform s_load of each X row, coalesced stores.
// ---------------------------------------------------------------------------
#define ROWS_PER_BLOCK 32

__global__ __launch_bounds__(256) void head_kernel(
    const float* __restrict__ xin,
    const float* __restrict__ Wh,
    const float* __restrict__ bh,
    float* __restrict__ out)
{
    const int tid = threadIdx.x;
    const int col = tid;
    float wh[DIM];
    #pragma unroll
    for (int d = 0; d < DIM; ++d) wh[d] = Wh[d * VOCAB + col];
    const float bhv = bh[col];

    const size_t row0 = (size_t)blockIdx.x * ROWS_PER_BLOCK;
    #pragma unroll 4
    for (int r = 0; r < ROWS_PER_BLOCK; ++r) {
        const float* xr = xin + (row0 + r) * DIM;  // wave-uniform address
        float acc = bhv;
        #pragma unroll
        for (int d = 0; d < DIM; ++d) acc += xr[d] * wh[d];
        out[(row0 + r) * VOCAB + col] = acc;
    }
}

// ---------------------------------------------------------------------------
// Fallback (ws too small): single-pass per-row body + per-column head.
// ---------------------------------------------------------------------------
#define ITEMS_PER_BLOCK 32
#define ITEM_STRIDE 136

__global__ __launch_bounds__(256) void fused_fallback_kernel(
    const int* __restrict__ x,
    const float* __restrict__ token_embed,
    const float* __restrict__ pos_embed,
    const float* __restrict__ Wq, const float* __restrict__ bq,
    const float* __restrict__ Wk, const float* __restrict__ bk,
    const float* __restrict__ Wv, const float* __restrict__ bv,
    const float* __restrict__ Wo, const float* __restrict__ bo,
    const float* __restrict__ W1, const float* __restrict__ b1,
    const float* __restrict__ W2, const float* __restrict__ b2,
    const float* __restrict__ Wh, const float* __restrict__ bh,
    float* __restrict__ out)
{
    __shared__ float sK[ITEMS_PER_BLOCK * ITEM_STRIDE];
    __shared__ float sV[ITEMS_PER_BLOCK * ITEM_STRIDE];

    const int tid = threadIdx.x;
    const int i = tid >> 3;
    const int n = tid & 7;
    const int b = blockIdx.x * ITEMS_PER_BLOCK + i;

    float X[DIM];
    {
        const int idx = x[b * SEQ + n];
        const float4* te = (const float4*)(token_embed + idx * DIM);
        const float4* pe = (const float4*)(pos_embed + n * DIM);
        #pragma unroll
        for (int j = 0; j < 4; ++j) {
            float4 a = te[j];
            float4 p = pe[j];
            X[4*j+0] = a.x + p.x; X[4*j+1] = a.y + p.y;
            X[4*j+2] = a.z + p.z; X[4*j+3] = a.w + p.w;
        }
    }

    float Q[DIM], Kr[DIM], Vr[DIM];
    #pragma unroll
    for (int e = 0; e < DIM; ++e) {
        float qq = bq[e], kk = bk[e], vv = bv[e];
        #pragma unroll
        for (int d = 0; d < DIM; ++d) {
            qq += X[d] * Wq[d * DIM + e];
            kk += X[d] * Wk[d * DIM + e];
            vv += X[d] * Wv[d * DIM + e];
        }
        Q[e] = qq; Kr[e] = kk; Vr[e] = vv;
    }
    {
        float* kdst = sK + i * ITEM_STRIDE + n * DIM;
        float* vdst = sV + i * ITEM_STRIDE + n * DIM;
        #pragma unroll
        for (int j = 0; j < 4; ++j) {
            float4 kk, vv;
            kk.x = Kr[4*j+0]; kk.y = Kr[4*j+1]; kk.z = Kr[4*j+2]; kk.w = Kr[4*j+3];
            vv.x = Vr[4*j+0]; vv.y = Vr[4*j+1]; vv.z = Vr[4*j+2]; vv.w = Vr[4*j+3];
            ((float4*)kdst)[j] = kk;
            ((float4*)vdst)[j] = vv;
        }
    }
    __syncthreads();

    float sc[SEQ];
    #pragma unroll
    for (int m = 0; m < SEQ; ++m) {
        const float* kr = sK + i * ITEM_STRIDE + m * DIM;
        float s = 0.f;
        #pragma unroll
        for (int d = 0; d < DIM; ++d) s += Q[d] * kr[d];
        sc[m] = s * 0.25f;
    }
    float mx = sc[0];
    #pragma unroll
    for (int m = 1; m < SEQ; ++m) mx = fmaxf(mx, sc[m]);
    float sum = 0.f;
    #pragma unroll
    for (int m = 0; m < SEQ; ++m) { sc[m] = __expf(sc[m] - mx); sum += sc[m]; }
    const float inv = 1.0f / sum;

    float at[DIM];
    #pragma unroll
    for (int d = 0; d < DIM; ++d) at[d] = 0.f;
    #pragma unroll
    for (int m = 0; m < SEQ; ++m) {
        const float w = sc[m] * inv;
        const float* vr = sV + i * ITEM_STRIDE + m * DIM;
        #pragma unroll
        for (int d = 0; d < DIM; ++d) at[d] += w * vr[d];
    }

    float X1[DIM];
    #pragma unroll
    for (int e = 0; e < DIM; ++e) {
        float o = bo[e];
        #pragma unroll
        for (int d = 0; d < DIM; ++d) o += at[d] * Wo[d * DIM + e];
        X1[e] = X[e] + o;
    }
    float h[FF];
    #pragma unroll
    for (int f = 0; f < FF; ++f) {
        float a = b1[f];
        #pragma unroll
        for (int d = 0; d < DIM; ++d) a += X1[d] * W1[d * FF + f];
        h[f] = fmaxf(a, 0.f);
    }
    float X2[DIM];
    #pragma unroll
    for (int e = 0; e < DIM; ++e) {
        float a = b2[e];
        #pragma unroll
        for (int f = 0; f < FF; ++f) a += h[f] * W2[f * DIM + e];
        X2[e] = X1[e] + a;
    }

    __syncthreads();
    {
        float* xdst = sK + i * ITEM_STRIDE + n * DIM;
        #pragma unroll
        for (int j = 0; j < 4; ++j) {
            float4 xx;
            xx.x = X2[4*j+0]; xx.y = X2[4*j+1]; xx.z = X2[4*j+2]; xx.w = X2[4*j+3];
            ((float4*)xdst)[j] = xx;
        }
    }
    __syncthreads();

    float wh[DIM];
    #pragma unroll
    for (int d = 0; d < DIM; ++d) wh[d] = Wh[d * VOCAB + tid];
    const float bhv = bh[tid];

    const size_t obase = (size_t)blockIdx.x * (ITEMS_PER_BLOCK * SEQ) * VOCAB + tid;
    #pragma unroll 4
    for (int r = 0; r < ITEMS_PER_BLOCK * SEQ; ++r) {
        const float* xr = sK + (r >> 3) * ITEM_STRIDE + (r & 7) * DIM;
        float acc = bhv;
        #pragma unroll
        for (int d = 0; d < DIM; ++d) acc += xr[d] * wh[d];
        out[obase + (size_t)r * VOCAB] = acc;
    }
}

extern "C" void kernel_launch(void* const* d_in, const int* in_sizes, int n_in,
                              void* d_out, int out_size, void* d_ws, size_t ws_size,
                              hipStream_t stream) {
    const int*   x           = (const int*)  d_in[0];
    const float* token_embed = (const float*)d_in[1];
    const float* pos_embed   = (const float*)d_in[2];
    const float* Wq = (const float*)d_in[3];
    const float* bq = (const float*)d_in[4];
    const float* Wk = (const float*)d_in[5];
    const float* bk = (const float*)d_in[6];
    const float* Wv = (const float*)d_in[7];
    const float* bv = (const float*)d_in[8];
    const float* Wo = (const float*)d_in[9];
    const float* bo = (const float*)d_in[10];
    const float* W1 = (const float*)d_in[11];
    const float* b1 = (const float*)d_in[12];
    const float* W2 = (const float*)d_in[13];
    const float* b2 = (const float*)d_in[14];
    const float* Wh = (const float*)d_in[15];
    const float* bh = (const float*)d_in[16];
    float* out = (float*)d_out;

    const int B = in_sizes[0] / SEQ;                 // 32768
    const int nrows = B * SEQ;                       // 262144
    const size_t xws_bytes = (size_t)nrows * DIM * sizeof(float);      // 16 MB
    const size_t ws_needed = xws_bytes + PW_TOT * sizeof(uint32_t);    // +4 KB

    if (ws_size >= ws_needed) {
        float* xws = (float*)d_ws;
        uint32_t* pw = (uint32_t*)((char*)d_ws + xws_bytes);
        pack_weights_kernel<<<PW_TOT / 256, 256, 0, stream>>>(
            Wq, Wk, Wv, Wo, W1, W2, pw);
        body_kernel<<<nrows / 256, 256, 0, stream>>>(
            x, token_embed, pos_embed, pw, bq, bk, bv, bo, b1, b2, xws);
        head_kernel<<<nrows / ROWS_PER_BLOCK, 256, 0, stream>>>(
            xws, Wh, bh, out);
    } else {
        fused_fallback_kernel<<<B / ITEMS_PER_BLOCK, 256, 0, stream>>>(
            x, token_embed, pos_embed, Wq, bq, Wk, bk, Wv, bv, Wo, bo,
            W1, b1, W2, b2, Wh, bh, out);
    }
}

// Round 10
// 96.248 us; speedup vs baseline: 2.0715x; 1.5968x over previous
//
#include <hip/hip_runtime.h>
#include <stdint.h>

#define SEQ 8
#define DIM 16
#define FF 32
#define VOCAB 256

// ds_swizzle XOR butterfly on a float (src_lane = lane ^ T, T<8 stays within
// the 8-lane item group). BitMode offset = (xor<<10) | (or<<5) | and, and=0x1F.
#define SWZF(val, imm) __int_as_float(__builtin_amdgcn_ds_swizzle(__float_as_int(val), (imm)))

// readlane broadcast: weight w lives in lane `l` of VGPR `v`; returns it as a
// wave-uniform value (SGPR). l is compile-time after unrolling.
__device__ __forceinline__ float rl(float v, int l) {
    return __uint_as_float(__builtin_amdgcn_readlane(__float_as_uint(v), l));
}

// ---------------------------------------------------------------------------
// Body v7 = round-4 swizzle body with weights PERSISTED IN VGPRS.
// Theory: the body's 48us wall (vs ~10us FMA issue) is weight re-delivery:
// every wave re-streams ~2k weight dwords through s_load (or LDS/VMEM - all
// measured worse), and at ~11 waves/CU the ~250cyc latency chains never hide.
// Fix: all 2176 weight floats fit in 32 VGPRs spread across 64 lanes
// (wreg[j] = W[64j + lane], loaded ONCE, coalesced). Each use is
// v_readlane_b32 (register source, no memory latency, constant lane) feeding
// v_fmac as an SGPR operand. VALU doubles (~20us) but the stall vanishes.
// ---------------------------------------------------------------------------
__global__ __launch_bounds__(256, 4) void body_kernel(
    const int* __restrict__ x,
    const float* __restrict__ token_embed,
    const float* __restrict__ pos_embed,
    const float* __restrict__ Wq, const float* __restrict__ bq,
    const float* __restrict__ Wk, const float* __restrict__ bk,
    const float* __restrict__ Wv, const float* __restrict__ bv,
    const float* __restrict__ Wo, const float* __restrict__ bo,
    const float* __restrict__ W1, const float* __restrict__ b1,
    const float* __restrict__ W2, const float* __restrict__ b2,
    float* __restrict__ xout)
{
    const int tid  = threadIdx.x;
    const int lane = tid & 63;
    const int n    = tid & 7;                                // seq position
    const size_t row = (size_t)blockIdx.x * 256 + tid;       // global row id

    // ---------------- persist all weights in VGPRs (one-time) ----------------
    float wqr[4], wkr[4], wvr[4], wor[4], w1r[8], w2r[8];
    #pragma unroll
    for (int j = 0; j < 4; ++j) {
        wqr[j] = Wq[64 * j + lane];
        wkr[j] = Wk[64 * j + lane];
        wvr[j] = Wv[64 * j + lane];
        wor[j] = Wo[64 * j + lane];
    }
    #pragma unroll
    for (int j = 0; j < 8; ++j) {
        w1r[j] = W1[64 * j + lane];
        w2r[j] = W2[64 * j + lane];
    }

    // ---------------- embedding + positional ----------------
    float X[DIM];
    {
        const int idx = x[row];
        const float4* te = (const float4*)(token_embed + (size_t)idx * DIM);
        const float4* pe = (const float4*)(pos_embed + n * DIM);
        #pragma unroll
        for (int j = 0; j < 4; ++j) {
            float4 a = te[j];
            float4 p = pe[j];
            X[4*j+0] = a.x + p.x;
            X[4*j+1] = a.y + p.y;
            X[4*j+2] = a.z + p.z;
            X[4*j+3] = a.w + p.w;
        }
    }

    // ---------------- QKV: outer-product over d, 48 acc chains ----------------
    float q[DIM], k[DIM], v[DIM];
    #pragma unroll
    for (int e = 0; e < DIM; ++e) { q[e] = bq[e]; k[e] = bk[e]; v[e] = bv[e]; }
    #pragma unroll
    for (int d = 0; d < DIM; ++d) {
        const float xd = X[d];
        #pragma unroll
        for (int e = 0; e < DIM; ++e) {
            const int i = d * DIM + e;          // 0..255, compile-time
            q[e] += xd * rl(wqr[i >> 6], i & 63);
            k[e] += xd * rl(wkr[i >> 6], i & 63);
            v[e] += xd * rl(wvr[i >> 6], i & 63);
        }
    }

    // ---------------- attention scores via XOR butterfly ----------------
    float sc[SEQ];
    {
        float s = 0.f;
        #pragma unroll
        for (int d = 0; d < DIM; ++d) s += q[d] * k[d];      // t = 0 (self)
        sc[0] = s * 0.25f;
    }
    #define SCORE_PHASE(T, IMM)                                   \
    {                                                             \
        float s = 0.f;                                            \
        _Pragma("unroll")                                         \
        for (int d = 0; d < DIM; ++d) s += q[d] * SWZF(k[d], IMM);\
        sc[T] = s * 0.25f;                                        \
    }
    SCORE_PHASE(1, 0x041F)
    SCORE_PHASE(2, 0x081F)
    SCORE_PHASE(3, 0x0C1F)
    SCORE_PHASE(4, 0x101F)
    SCORE_PHASE(5, 0x141F)
    SCORE_PHASE(6, 0x181F)
    SCORE_PHASE(7, 0x1C1F)
    #undef SCORE_PHASE

    // ---------------- softmax over the 8 scores (per-lane) ----------------
    float mx = sc[0];
    #pragma unroll
    for (int m = 1; m < SEQ; ++m) mx = fmaxf(mx, sc[m]);
    float sum = 0.f;
    float w[SEQ];
    #pragma unroll
    for (int m = 0; m < SEQ; ++m) { w[m] = __expf(sc[m] - mx); sum += w[m]; }
    const float inv = 1.0f / sum;
    #pragma unroll
    for (int m = 0; m < SEQ; ++m) w[m] *= inv;

    // ---------------- PV via XOR butterfly ----------------
    float at[DIM];
    #pragma unroll
    for (int d = 0; d < DIM; ++d) at[d] = w[0] * v[d];       // t = 0 (self)
    #define PV_PHASE(T, IMM)                                      \
    {                                                             \
        const float wt = w[T];                                    \
        _Pragma("unroll")                                         \
        for (int d = 0; d < DIM; ++d) at[d] += wt * SWZF(v[d], IMM);\
    }
    PV_PHASE(1, 0x041F)
    PV_PHASE(2, 0x081F)
    PV_PHASE(3, 0x0C1F)
    PV_PHASE(4, 0x101F)
    PV_PHASE(5, 0x141F)
    PV_PHASE(6, 0x181F)
    PV_PHASE(7, 0x1C1F)
    #undef PV_PHASE

    // ---------------- O projection + residual ----------------
    float X1[DIM];
    #pragma unroll
    for (int e = 0; e < DIM; ++e) X1[e] = X[e] + bo[e];
    #pragma unroll
    for (int d = 0; d < DIM; ++d) {
        const float ad = at[d];
        #pragma unroll
        for (int e = 0; e < DIM; ++e) {
            const int i = d * DIM + e;
            X1[e] += ad * rl(wor[i >> 6], i & 63);
        }
    }

    // ---------------- FFN + residual ----------------
    float h[FF];
    #pragma unroll
    for (int f = 0; f < FF; ++f) h[f] = b1[f];
    #pragma unroll
    for (int d = 0; d < DIM; ++d) {
        const float xd = X1[d];
        #pragma unroll
        for (int f = 0; f < FF; ++f) {
            const int i = d * FF + f;           // 0..511
            h[f] += xd * rl(w1r[i >> 6], i & 63);
        }
    }
    #pragma unroll
    for (int f = 0; f < FF; ++f) h[f] = fmaxf(h[f], 0.f);

    float X2[DIM];
    #pragma unroll
    for (int e = 0; e < DIM; ++e) X2[e] = X1[e] + b2[e];
    #pragma unroll
    for (int f = 0; f < FF; ++f) {
        const float hf = h[f];
        #pragma unroll
        for (int e = 0; e < DIM; ++e) {
            const int i = f * DIM + e;          // 0..511
            X2[e] += hf * rl(w2r[i >> 6], i & 63);
        }
    }

    // ---------------- write X2 row ----------------
    float4* dst = (float4*)(xout + row * DIM);
    #pragma unroll
    for (int j = 0; j < 4; ++j) {
        float4 xx;
        xx.x = X2[4*j+0]; xx.y = X2[4*j+1]; xx.z = X2[4*j+2]; xx.w = X2[4*j+3];
        dst[j] = xx;
    }
}

// ---------------------------------------------------------------------------
// Head v1 (proven ~49us): vocab GEMM [R,16] @ [16,256] + bias. 1 col/lane,
// 16 weight VGPRs, wave-uniform s_load of each X row, coalesced stores.
// 8192 blocks = 32768 waves -> 8 waves/SIMD.
// ---------------------------------------------------------------------------
#define ROWS_PER_BLOCK 32

__global__ __launch_bounds__(256) void head_kernel(
    const float* __restrict__ xin,
    const float* __restrict__ Wh,
    const float* __restrict__ bh,
    float* __restrict__ out)
{
    const int tid = threadIdx.x;
    const int col = tid;
    float wh[DIM];
    #pragma unroll
    for (int d = 0; d < DIM; ++d) wh[d] = Wh[d * VOCAB + col];
    const float bhv = bh[col];

    const size_t row0 = (size_t)blockIdx.x * ROWS_PER_BLOCK;
    #pragma unroll 4
    for (int r = 0; r < ROWS_PER_BLOCK; ++r) {
        const float* xr = xin + (row0 + r) * DIM;  // wave-uniform address
        float acc = bhv;
        #pragma unroll
        for (int d = 0; d < DIM; ++d) acc += xr[d] * wh[d];
        out[(row0 + r) * VOCAB + col] = acc;
    }
}

// ---------------------------------------------------------------------------
// Fallback (ws too small): single-pass per-row body + per-column head.
// ---------------------------------------------------------------------------
#define ITEMS_PER_BLOCK 32
#define ITEM_STRIDE 136

__global__ __launch_bounds__(256) void fused_fallback_kernel(
    const int* __restrict__ x,
    const float* __restrict__ token_embed,
    const float* __restrict__ pos_embed,
    const float* __restrict__ Wq, const float* __restrict__ bq,
    const float* __restrict__ Wk, const float* __restrict__ bk,
    const float* __restrict__ Wv, const float* __restrict__ bv,
    const float* __restrict__ Wo, const float* __restrict__ bo,
    const float* __restrict__ W1, const float* __restrict__ b1,
    const float* __restrict__ W2, const float* __restrict__ b2,
    const float* __restrict__ Wh, const float* __restrict__ bh,
    float* __restrict__ out)
{
    __shared__ float sK[ITEMS_PER_BLOCK * ITEM_STRIDE];
    __shared__ float sV[ITEMS_PER_BLOCK * ITEM_STRIDE];

    const int tid = threadIdx.x;
    const int i = tid >> 3;
    const int n = tid & 7;
    const int b = blockIdx.x * ITEMS_PER_BLOCK + i;

    float X[DIM];
    {
        const int idx = x[b * SEQ + n];
        const float4* te = (const float4*)(token_embed + idx * DIM);
        const float4* pe = (const float4*)(pos_embed + n * DIM);
        #pragma unroll
        for (int j = 0; j < 4; ++j) {
            float4 a = te[j];
            float4 p = pe[j];
            X[4*j+0] = a.x + p.x; X[4*j+1] = a.y + p.y;
            X[4*j+2] = a.z + p.z; X[4*j+3] = a.w + p.w;
        }
    }

    float Q[DIM], Kr[DIM], Vr[DIM];
    #pragma unroll
    for (int e = 0; e < DIM; ++e) {
        float qq = bq[e], kk = bk[e], vv = bv[e];
        #pragma unroll
        for (int d = 0; d < DIM; ++d) {
            qq += X[d] * Wq[d * DIM + e];
            kk += X[d] * Wk[d * DIM + e];
            vv += X[d] * Wv[d * DIM + e];
        }
        Q[e] = qq; Kr[e] = kk; Vr[e] = vv;
    }
    {
        float* kdst = sK + i * ITEM_STRIDE + n * DIM;
        float* vdst = sV + i * ITEM_STRIDE + n * DIM;
        #pragma unroll
        for (int j = 0; j < 4; ++j) {
            float4 kk, vv;
            kk.x = Kr[4*j+0]; kk.y = Kr[4*j+1]; kk.z = Kr[4*j+2]; kk.w = Kr[4*j+3];
            vv.x = Vr[4*j+0]; vv.y = Vr[4*j+1]; vv.z = Vr[4*j+2]; vv.w = Vr[4*j+3];
            ((float4*)kdst)[j] = kk;
            ((float4*)vdst)[j] = vv;
        }
    }
    __syncthreads();

    float sc[SEQ];
    #pragma unroll
    for (int m = 0; m < SEQ; ++m) {
        const float* kr = sK + i * ITEM_STRIDE + m * DIM;
        float s = 0.f;
        #pragma unroll
        for (int d = 0; d < DIM; ++d) s += Q[d] * kr[d];
        sc[m] = s * 0.25f;
    }
    float mx = sc[0];
    #pragma unroll
    for (int m = 1; m < SEQ; ++m) mx = fmaxf(mx, sc[m]);
    float sum = 0.f;
    #pragma unroll
    for (int m = 0; m < SEQ; ++m) { sc[m] = __expf(sc[m] - mx); sum += sc[m]; }
    const float inv = 1.0f / sum;

    float at[DIM];
    #pragma unroll
    for (int d = 0; d < DIM; ++d) at[d] = 0.f;
    #pragma unroll
    for (int m = 0; m < SEQ; ++m) {
        const float w = sc[m] * inv;
        const float* vr = sV + i * ITEM_STRIDE + m * DIM;
        #pragma unroll
        for (int d = 0; d < DIM; ++d) at[d] += w * vr[d];
    }

    float X1[DIM];
    #pragma unroll
    for (int e = 0; e < DIM; ++e) {
        float o = bo[e];
        #pragma unroll
        for (int d = 0; d < DIM; ++d) o += at[d] * Wo[d * DIM + e];
        X1[e] = X[e] + o;
    }
    float h[FF];
    #pragma unroll
    for (int f = 0; f < FF; ++f) {
        float a = b1[f];
        #pragma unroll
        for (int d = 0; d < DIM; ++d) a += X1[d] * W1[d * FF + f];
        h[f] = fmaxf(a, 0.f);
    }
    float X2[DIM];
    #pragma unroll
    for (int e = 0; e < DIM; ++e) {
        float a = b2[e];
        #pragma unroll
        for (int f = 0; f < FF; ++f) a += h[f] * W2[f * DIM + e];
        X2[e] = X1[e] + a;
    }

    __syncthreads();
    {
        float* xdst = sK + i * ITEM_STRIDE + n * DIM;
        #pragma unroll
        for (int j = 0; j < 4; ++j) {
            float4 xx;
            xx.x = X2[4*j+0]; xx.y = X2[4*j+1]; xx.z = X2[4*j+2]; xx.w = X2[4*j+3];
            ((float4*)xdst)[j] = xx;
        }
    }
    __syncthreads();

    float wh[DIM];
    #pragma unroll
    for (int d = 0; d < DIM; ++d) wh[d] = Wh[d * VOCAB + tid];
    const float bhv = bh[tid];

    const size_t obase = (size_t)blockIdx.x * (ITEMS_PER_BLOCK * SEQ) * VOCAB + tid;
    #pragma unroll 4
    for (int r = 0; r < ITEMS_PER_BLOCK * SEQ; ++r) {
        const float* xr = sK + (r >> 3) * ITEM_STRIDE + (r & 7) * DIM;
        float acc = bhv;
        #pragma unroll
        for (int d = 0; d < DIM; ++d) acc += xr[d] * wh[d];
        out[obase + (size_t)r * VOCAB] = acc;
    }
}

extern "C" void kernel_launch(void* const* d_in, const int* in_sizes, int n_in,
                              void* d_out, int out_size, void* d_ws, size_t ws_size,
                              hipStream_t stream) {
    const int*   x           = (const int*)  d_in[0];
    const float* token_embed = (const float*)d_in[1];
    const float* pos_embed   = (const float*)d_in[2];
    const float* Wq = (const float*)d_in[3];
    const float* bq = (const float*)d_in[4];
    const float* Wk = (const float*)d_in[5];
    const float* bk = (const float*)d_in[6];
    const float* Wv = (const float*)d_in[7];
    const float* bv = (const float*)d_in[8];
    const float* Wo = (const float*)d_in[9];
    const float* bo = (const float*)d_in[10];
    const float* W1 = (const float*)d_in[11];
    const float* b1 = (const float*)d_in[12];
    const float* W2 = (const float*)d_in[13];
    const float* b2 = (const float*)d_in[14];
    const float* Wh = (const float*)d_in[15];
    const float* bh = (const float*)d_in[16];
    float* out = (float*)d_out;

    const int B = in_sizes[0] / SEQ;                 // 32768
    const int nrows = B * SEQ;                       // 262144
    const size_t ws_needed = (size_t)nrows * DIM * sizeof(float);  // 16 MB

    if (ws_size >= ws_needed) {
        float* xws = (float*)d_ws;
        body_kernel<<<nrows / 256, 256, 0, stream>>>(
            x, token_embed, pos_embed, Wq, bq, Wk, bk, Wv, bv, Wo, bo,
            W1, b1, W2, b2, xws);
        head_kernel<<<nrows / ROWS_PER_BLOCK, 256, 0, stream>>>(
            xws, Wh, bh, out);
    } else {
        fused_fallback_kernel<<<B / ITEMS_PER_BLOCK, 256, 0, stream>>>(
            x, token_embed, pos_embed, Wq, bq, Wk, bk, Wv, bv, Wo, bo,
            W1, b1, W2, b2, Wh, bh, out);
    }
}

// Round 11
// 91.180 us; speedup vs baseline: 2.1866x; 1.0556x over previous
//
#include <hip/hip_runtime.h>
#include <hip/hip_fp16.h>
#include <stdint.h>

#define SEQ 8
#define DIM 16
#define FF 32
#define VOCAB 256

typedef _Float16 f16x4 __attribute__((ext_vector_type(4)));
typedef float f32x4 __attribute__((ext_vector_type(4)));

// ds_swizzle XOR butterfly on a float (src_lane = lane ^ T, T<8 stays within
// the 8-lane item group). BitMode offset = (xor<<10) | (or<<5) | and, and=0x1F.
#define SWZF(val, imm) __int_as_float(__builtin_amdgcn_ds_swizzle(__float_as_int(val), (imm)))

// readlane broadcast: weight lives in lane `l` of VGPR `v` (l compile-time).
__device__ __forceinline__ float rl(float v, int l) {
    return __uint_as_float(__builtin_amdgcn_readlane(__float_as_uint(v), l));
}

// ---------------------------------------------------------------------------
// Pre-pass: pack Wh (f32 [16][256]) into f16 MFMA B-fragment layout:
// bpk[t*64 + l] = 4 f16 {Wh[k0+i][t*16 + (l&15)]}, k0 = (l>>4)*4.
// 1024 entries x 8B = 8KB.
// ---------------------------------------------------------------------------
__global__ __launch_bounds__(256) void pack_head_kernel(
    const float* __restrict__ Wh, uint64_t* __restrict__ bpk)
{
    const int i = blockIdx.x * 256 + threadIdx.x;   // 0..1023
    const int t = i >> 6, l = i & 63;
    const int col = t * 16 + (l & 15);
    const int k0 = (l >> 4) * 4;
    uint32_t w0 = (uint32_t)__half_as_ushort(__float2half(Wh[(k0 + 0) * VOCAB + col]))
                | ((uint32_t)__half_as_ushort(__float2half(Wh[(k0 + 1) * VOCAB + col])) << 16);
    uint32_t w1 = (uint32_t)__half_as_ushort(__float2half(Wh[(k0 + 2) * VOCAB + col]))
                | ((uint32_t)__half_as_ushort(__float2half(Wh[(k0 + 3) * VOCAB + col])) << 16);
    bpk[i] = (uint64_t)w0 | ((uint64_t)w1 << 32);
}

// ---------------------------------------------------------------------------
// Body v8 = R10 readlane body (proven ~47us); tail now emits X2 as f16 in
// MFMA A-fragment layout: afrag[tile*64 + c*16 + (row&15)] = 4 f16 of
// X2[4c..4c+3], tile = row>>4. (A: lane l holds A[m=l&15][k=(l>>4)*4+i].)
// ---------------------------------------------------------------------------
__global__ __launch_bounds__(256, 4) void body_kernel(
    const int* __restrict__ x,
    const float* __restrict__ token_embed,
    const float* __restrict__ pos_embed,
    const float* __restrict__ Wq, const float* __restrict__ bq,
    const float* __restrict__ Wk, const float* __restrict__ bk,
    const float* __restrict__ Wv, const float* __restrict__ bv,
    const float* __restrict__ Wo, const float* __restrict__ bo,
    const float* __restrict__ W1, const float* __restrict__ b1,
    const float* __restrict__ W2, const float* __restrict__ b2,
    uint64_t* __restrict__ afrag)
{
    const int tid  = threadIdx.x;
    const int lane = tid & 63;
    const int n    = tid & 7;
    const size_t row = (size_t)blockIdx.x * 256 + tid;

    // ---------------- persist all weights in VGPRs (one-time) ----------------
    float wqr[4], wkr[4], wvr[4], wor[4], w1r[8], w2r[8];
    #pragma unroll
    for (int j = 0; j < 4; ++j) {
        wqr[j] = Wq[64 * j + lane];
        wkr[j] = Wk[64 * j + lane];
        wvr[j] = Wv[64 * j + lane];
        wor[j] = Wo[64 * j + lane];
    }
    #pragma unroll
    for (int j = 0; j < 8; ++j) {
        w1r[j] = W1[64 * j + lane];
        w2r[j] = W2[64 * j + lane];
    }

    // ---------------- embedding + positional ----------------
    float X[DIM];
    {
        const int idx = x[row];
        const float4* te = (const float4*)(token_embed + (size_t)idx * DIM);
        const float4* pe = (const float4*)(pos_embed + n * DIM);
        #pragma unroll
        for (int j = 0; j < 4; ++j) {
            float4 a = te[j];
            float4 p = pe[j];
            X[4*j+0] = a.x + p.x;
            X[4*j+1] = a.y + p.y;
            X[4*j+2] = a.z + p.z;
            X[4*j+3] = a.w + p.w;
        }
    }

    // ---------------- QKV ----------------
    float q[DIM], k[DIM], v[DIM];
    #pragma unroll
    for (int e = 0; e < DIM; ++e) { q[e] = bq[e]; k[e] = bk[e]; v[e] = bv[e]; }
    #pragma unroll
    for (int d = 0; d < DIM; ++d) {
        const float xd = X[d];
        #pragma unroll
        for (int e = 0; e < DIM; ++e) {
            const int i = d * DIM + e;
            q[e] += xd * rl(wqr[i >> 6], i & 63);
            k[e] += xd * rl(wkr[i >> 6], i & 63);
            v[e] += xd * rl(wvr[i >> 6], i & 63);
        }
    }

    // ---------------- attention scores via XOR butterfly ----------------
    float sc[SEQ];
    {
        float s = 0.f;
        #pragma unroll
        for (int d = 0; d < DIM; ++d) s += q[d] * k[d];
        sc[0] = s * 0.25f;
    }
    #define SCORE_PHASE(T, IMM)                                   \
    {                                                             \
        float s = 0.f;                                            \
        _Pragma("unroll")                                         \
        for (int d = 0; d < DIM; ++d) s += q[d] * SWZF(k[d], IMM);\
        sc[T] = s * 0.25f;                                        \
    }
    SCORE_PHASE(1, 0x041F)
    SCORE_PHASE(2, 0x081F)
    SCORE_PHASE(3, 0x0C1F)
    SCORE_PHASE(4, 0x101F)
    SCORE_PHASE(5, 0x141F)
    SCORE_PHASE(6, 0x181F)
    SCORE_PHASE(7, 0x1C1F)
    #undef SCORE_PHASE

    // ---------------- softmax ----------------
    float mx = sc[0];
    #pragma unroll
    for (int m = 1; m < SEQ; ++m) mx = fmaxf(mx, sc[m]);
    float sum = 0.f;
    float w[SEQ];
    #pragma unroll
    for (int m = 0; m < SEQ; ++m) { w[m] = __expf(sc[m] - mx); sum += w[m]; }
    const float inv = 1.0f / sum;
    #pragma unroll
    for (int m = 0; m < SEQ; ++m) w[m] *= inv;

    // ---------------- PV via XOR butterfly ----------------
    float at[DIM];
    #pragma unroll
    for (int d = 0; d < DIM; ++d) at[d] = w[0] * v[d];
    #define PV_PHASE(T, IMM)                                      \
    {                                                             \
        const float wt = w[T];                                    \
        _Pragma("unroll")                                         \
        for (int d = 0; d < DIM; ++d) at[d] += wt * SWZF(v[d], IMM);\
    }
    PV_PHASE(1, 0x041F)
    PV_PHASE(2, 0x081F)
    PV_PHASE(3, 0x0C1F)
    PV_PHASE(4, 0x101F)
    PV_PHASE(5, 0x141F)
    PV_PHASE(6, 0x181F)
    PV_PHASE(7, 0x1C1F)
    #undef PV_PHASE

    // ---------------- O projection + residual ----------------
    float X1[DIM];
    #pragma unroll
    for (int e = 0; e < DIM; ++e) X1[e] = X[e] + bo[e];
    #pragma unroll
    for (int d = 0; d < DIM; ++d) {
        const float ad = at[d];
        #pragma unroll
        for (int e = 0; e < DIM; ++e) {
            const int i = d * DIM + e;
            X1[e] += ad * rl(wor[i >> 6], i & 63);
        }
    }

    // ---------------- FFN + residual ----------------
    float h[FF];
    #pragma unroll
    for (int f = 0; f < FF; ++f) h[f] = b1[f];
    #pragma unroll
    for (int d = 0; d < DIM; ++d) {
        const float xd = X1[d];
        #pragma unroll
        for (int f = 0; f < FF; ++f) {
            const int i = d * FF + f;
            h[f] += xd * rl(w1r[i >> 6], i & 63);
        }
    }
    #pragma unroll
    for (int f = 0; f < FF; ++f) h[f] = fmaxf(h[f], 0.f);

    float X2[DIM];
    #pragma unroll
    for (int e = 0; e < DIM; ++e) X2[e] = X1[e] + b2[e];
    #pragma unroll
    for (int f = 0; f < FF; ++f) {
        const float hf = h[f];
        #pragma unroll
        for (int e = 0; e < DIM; ++e) {
            const int i = f * DIM + e;
            X2[e] += hf * rl(w2r[i >> 6], i & 63);
        }
    }

    // ---------------- write X2 as f16 A-fragments ----------------
    uint32_t pk[8];
    #pragma unroll
    for (int j = 0; j < 8; ++j) {
        pk[j] = (uint32_t)__half_as_ushort(__float2half(X2[2*j]))
              | ((uint32_t)__half_as_ushort(__float2half(X2[2*j+1])) << 16);
    }
    const int tile = (int)(row >> 4);
    const int m    = (int)(row & 15);
    uint64_t* ab = afrag + (size_t)tile * 64 + m;
    #pragma unroll
    for (int c = 0; c < 4; ++c) {
        ab[c * 16] = (uint64_t)pk[2*c] | ((uint64_t)pk[2*c+1] << 32);
    }
}

// ---------------------------------------------------------------------------
// Head v3: f16 MFMA GEMM. Per wave: 2 row-tiles; per tile: 1 coalesced A-frag
// load + 16x { mfma_f32_16x16x16_f16 + 4 dword stores }. MFMA ~2us/CU total;
// the kernel is purely output-write-bound (~39us floor).
// D layout (verified m89): row=(l>>4)*4+j, col=l&15.
// ---------------------------------------------------------------------------
__global__ __launch_bounds__(256) void head_mfma_kernel(
    const f16x4* __restrict__ afrag,   // [ntiles][64]
    const f16x4* __restrict__ bpk,     // [16][64]
    const float* __restrict__ bh,
    float* __restrict__ out)
{
    const int tid = threadIdx.x;
    const int wv = tid >> 6, l = tid & 63;

    f16x4 Bf[16];
    #pragma unroll
    for (int t = 0; t < 16; ++t) Bf[t] = bpk[t * 64 + l];
    float bias[16];
    #pragma unroll
    for (int t = 0; t < 16; ++t) bias[t] = bh[t * 16 + (l & 15)];

    const int tile0 = blockIdx.x * 8 + wv * 2;
    #pragma unroll
    for (int tt = 0; tt < 2; ++tt) {
        const int tile = tile0 + tt;
        const f16x4 Af = afrag[(size_t)tile * 64 + l];
        float* obase = out + ((size_t)tile * 16 + ((l >> 4) * 4)) * VOCAB + (l & 15);
        #pragma unroll
        for (int t = 0; t < 16; ++t) {
            f32x4 acc = {bias[t], bias[t], bias[t], bias[t]};
            acc = __builtin_amdgcn_mfma_f32_16x16x16f16(Af, Bf[t], acc, 0, 0, 0);
            #pragma unroll
            for (int j = 0; j < 4; ++j)
                obase[(size_t)j * VOCAB + t * 16] = acc[j];
        }
    }
}

// ---------------------------------------------------------------------------
// Fallback (ws too small): single-pass per-row body + per-column head.
// ---------------------------------------------------------------------------
#define ITEMS_PER_BLOCK 32
#define ITEM_STRIDE 136

__global__ __launch_bounds__(256) void fused_fallback_kernel(
    const int* __restrict__ x,
    const float* __restrict__ token_embed,
    const float* __restrict__ pos_embed,
    const float* __restrict__ Wq, const float* __restrict__ bq,
    const float* __restrict__ Wk, const float* __restrict__ bk,
    const float* __restrict__ Wv, const float* __restrict__ bv,
    const float* __restrict__ Wo, const float* __restrict__ bo,
    const float* __restrict__ W1, const float* __restrict__ b1,
    const float* __restrict__ W2, const float* __restrict__ b2,
    const float* __restrict__ Wh, const float* __restrict__ bh,
    float* __restrict__ out)
{
    __shared__ float sK[ITEMS_PER_BLOCK * ITEM_STRIDE];
    __shared__ float sV[ITEMS_PER_BLOCK * ITEM_STRIDE];

    const int tid = threadIdx.x;
    const int i = tid >> 3;
    const int n = tid & 7;
    const int b = blockIdx.x * ITEMS_PER_BLOCK + i;

    float X[DIM];
    {
        const int idx = x[b * SEQ + n];
        const float4* te = (const float4*)(token_embed + idx * DIM);
        const float4* pe = (const float4*)(pos_embed + n * DIM);
        #pragma unroll
        for (int j = 0; j < 4; ++j) {
            float4 a = te[j];
            float4 p = pe[j];
            X[4*j+0] = a.x + p.x; X[4*j+1] = a.y + p.y;
            X[4*j+2] = a.z + p.z; X[4*j+3] = a.w + p.w;
        }
    }

    float Q[DIM], Kr[DIM], Vr[DIM];
    #pragma unroll
    for (int e = 0; e < DIM; ++e) {
        float qq = bq[e], kk = bk[e], vv = bv[e];
        #pragma unroll
        for (int d = 0; d < DIM; ++d) {
            qq += X[d] * Wq[d * DIM + e];
            kk += X[d] * Wk[d * DIM + e];
            vv += X[d] * Wv[d * DIM + e];
        }
        Q[e] = qq; Kr[e] = kk; Vr[e] = vv;
    }
    {
        float* kdst = sK + i * ITEM_STRIDE + n * DIM;
        float* vdst = sV + i * ITEM_STRIDE + n * DIM;
        #pragma unroll
        for (int j = 0; j < 4; ++j) {
            float4 kk, vv;
            kk.x = Kr[4*j+0]; kk.y = Kr[4*j+1]; kk.z = Kr[4*j+2]; kk.w = Kr[4*j+3];
            vv.x = Vr[4*j+0]; vv.y = Vr[4*j+1]; vv.z = Vr[4*j+2]; vv.w = Vr[4*j+3];
            ((float4*)kdst)[j] = kk;
            ((float4*)vdst)[j] = vv;
        }
    }
    __syncthreads();

    float sc[SEQ];
    #pragma unroll
    for (int m = 0; m < SEQ; ++m) {
        const float* kr = sK + i * ITEM_STRIDE + m * DIM;
        float s = 0.f;
        #pragma unroll
        for (int d = 0; d < DIM; ++d) s += Q[d] * kr[d];
        sc[m] = s * 0.25f;
    }
    float mx = sc[0];
    #pragma unroll
    for (int m = 1; m < SEQ; ++m) mx = fmaxf(mx, sc[m]);
    float sum = 0.f;
    #pragma unroll
    for (int m = 0; m < SEQ; ++m) { sc[m] = __expf(sc[m] - mx); sum += sc[m]; }
    const float inv = 1.0f / sum;

    float at[DIM];
    #pragma unroll
    for (int d = 0; d < DIM; ++d) at[d] = 0.f;
    #pragma unroll
    for (int m = 0; m < SEQ; ++m) {
        const float w = sc[m] * inv;
        const float* vr = sV + i * ITEM_STRIDE + m * DIM;
        #pragma unroll
        for (int d = 0; d < DIM; ++d) at[d] += w * vr[d];
    }

    float X1[DIM];
    #pragma unroll
    for (int e = 0; e < DIM; ++e) {
        float o = bo[e];
        #pragma unroll
        for (int d = 0; d < DIM; ++d) o += at[d] * Wo[d * DIM + e];
        X1[e] = X[e] + o;
    }
    float h[FF];
    #pragma unroll
    for (int f = 0; f < FF; ++f) {
        float a = b1[f];
        #pragma unroll
        for (int d = 0; d < DIM; ++d) a += X1[d] * W1[d * FF + f];
        h[f] = fmaxf(a, 0.f);
    }
    float X2[DIM];
    #pragma unroll
    for (int e = 0; e < DIM; ++e) {
        float a = b2[e];
        #pragma unroll
        for (int f = 0; f < FF; ++f) a += h[f] * W2[f * DIM + e];
        X2[e] = X1[e] + a;
    }

    __syncthreads();
    {
        float* xdst = sK + i * ITEM_STRIDE + n * DIM;
        #pragma unroll
        for (int j = 0; j < 4; ++j) {
            float4 xx;
            xx.x = X2[4*j+0]; xx.y = X2[4*j+1]; xx.z = X2[4*j+2]; xx.w = X2[4*j+3];
            ((float4*)xdst)[j] = xx;
        }
    }
    __syncthreads();

    float wh[DIM];
    #pragma unroll
    for (int d = 0; d < DIM; ++d) wh[d] = Wh[d * VOCAB + tid];
    const float bhv = bh[tid];

    const size_t obase = (size_t)blockIdx.x * (ITEMS_PER_BLOCK * SEQ) * VOCAB + tid;
    #pragma unroll 4
    for (int r = 0; r < ITEMS_PER_BLOCK * SEQ; ++r) {
        const float* xr = sK + (r >> 3) * ITEM_STRIDE + (r & 7) * DIM;
        float acc = bhv;
        #pragma unroll
        for (int d = 0; d < DIM; ++d) acc += xr[d] * wh[d];
        out[obase + (size_t)r * VOCAB] = acc;
    }
}

extern "C" void kernel_launch(void* const* d_in, const int* in_sizes, int n_in,
                              void* d_out, int out_size, void* d_ws, size_t ws_size,
                              hipStream_t stream) {
    const int*   x           = (const int*)  d_in[0];
    const float* token_embed = (const float*)d_in[1];
    const float* pos_embed   = (const float*)d_in[2];
    const float* Wq = (const float*)d_in[3];
    const float* bq = (const float*)d_in[4];
    const float* Wk = (const float*)d_in[5];
    const float* bk = (const float*)d_in[6];
    const float* Wv = (const float*)d_in[7];
    const float* bv = (const float*)d_in[8];
    const float* Wo = (const float*)d_in[9];
    const float* bo = (const float*)d_in[10];
    const float* W1 = (const float*)d_in[11];
    const float* b1 = (const float*)d_in[12];
    const float* W2 = (const float*)d_in[13];
    const float* b2 = (const float*)d_in[14];
    const float* Wh = (const float*)d_in[15];
    const float* bh = (const float*)d_in[16];
    float* out = (float*)d_out;

    const int B = in_sizes[0] / SEQ;                 // 32768
    const int nrows = B * SEQ;                       // 262144
    const int ntiles = nrows / 16;                   // 16384
    const size_t afrag_bytes = (size_t)ntiles * 64 * 8;          // 8 MB
    const size_t ws_needed = afrag_bytes + 16 * 64 * 8;          // +8 KB

    if (ws_size >= ws_needed) {
        uint64_t* afrag = (uint64_t*)d_ws;
        uint64_t* bpk   = (uint64_t*)((char*)d_ws + afrag_bytes);
        pack_head_kernel<<<4, 256, 0, stream>>>(Wh, bpk);
        body_kernel<<<nrows / 256, 256, 0, stream>>>(
            x, token_embed, pos_embed, Wq, bq, Wk, bk, Wv, bv, Wo, bo,
            W1, b1, W2, b2, afrag);
        head_mfma_kernel<<<ntiles / 8, 256, 0, stream>>>(
            (const f16x4*)afrag, (const f16x4*)bpk, bh, out);
    } else {
        fused_fallback_kernel<<<B / ITEMS_PER_BLOCK, 256, 0, stream>>>(
            x, token_embed, pos_embed, Wq, bq, Wk, bk, Wv, bv, Wo, bo,
            W1, b1, W2, b2, Wh, bh, out);
    }
}

// Round 13
// 55.239 us; speedup vs baseline: 3.6093x; 1.6507x over previous
//
#include <hip/hip_runtime.h>
#include <hip/hip_fp16.h>
#include <stdint.h>

#define SEQ 8
#define DIM 16
#define FF 32
#define VOCAB 256
#define TPW 4      // tiles (16 rows each) per wave
#define NFRAG 24   // 8 body fragments + 16 head fragments

typedef _Float16 f16x4 __attribute__((ext_vector_type(4)));
typedef float f32x4 __attribute__((ext_vector_type(4)));

#define SWZF(val, imm) __int_as_float(__builtin_amdgcn_ds_swizzle(__float_as_int(val), (imm)))
#define MFMA(a, b, c) __builtin_amdgcn_mfma_f32_16x16x16f16((a), (b), (c), 0, 0, 0)

__device__ __forceinline__ uint32_t pk2h(float a, float b) {
    return (uint32_t)__half_as_ushort(__float2half(a))
         | ((uint32_t)__half_as_ushort(__float2half(b)) << 16);
}
__device__ __forceinline__ f32x4 splat4(float s) {
    f32x4 r;
    r[0] = s; r[1] = s; r[2] = s; r[3] = s;
    return r;
}
__device__ __forceinline__ f16x4 cvt4(f32x4 a) {
    f16x4 r;
    r[0] = (_Float16)a[0]; r[1] = (_Float16)a[1];
    r[2] = (_Float16)a[2]; r[3] = (_Float16)a[3];
    return r;
}
__device__ __forceinline__ float bperm(int addr, float v) {
    return __int_as_float(__builtin_amdgcn_ds_bpermute(addr, __float_as_int(v)));
}

// ---------------------------------------------------------------------------
// Pack all weights into f16 MFMA fragments. Per-lane mapping (A and B
// operands share it, empirically validated in R11):
//   frag[l] reg i  <->  M[roff + (l>>4)*4 + i][coff + (l&15)]
// f: 0 Wq^T-as-A / 1 Wk^T-as-A / 2 Wv-as-B / 3 Wo-as-B (all 16x16, same map)
//    4,5 W1-as-A^T (col halves) / 6,7 W2^T-as-A (row halves) / 8..23 Wh-as-B.
// Note Wq^T fragment == Wq with the standard map read as-is for MFMA(Fq, Xf):
// frag reg i holds Wq[k][m]-style entries because "A^T as A" = swap of roles;
// here we simply load Wq row-major with the shared map, which realizes
// (Wq^T)[m][k] = Wq[k][m] when used as the A operand.
// ---------------------------------------------------------------------------
__global__ __launch_bounds__(256) void pack_frags_kernel(
    const float* __restrict__ Wq, const float* __restrict__ Wk,
    const float* __restrict__ Wv, const float* __restrict__ Wo,
    const float* __restrict__ W1, const float* __restrict__ W2,
    const float* __restrict__ Wh, uint64_t* __restrict__ pw)
{
    const int i = blockIdx.x * 256 + threadIdx.x;
    if (i >= NFRAG * 64) return;
    const int f = i >> 6, l = i & 63;
    const int k0 = (l >> 4) * 4, c = l & 15;
    const float* src; int ld, roff, coff;
    if      (f == 0) { src = Wq; ld = 16;  roff = 0;  coff = 0; }
    else if (f == 1) { src = Wk; ld = 16;  roff = 0;  coff = 0; }
    else if (f == 2) { src = Wv; ld = 16;  roff = 0;  coff = 0; }
    else if (f == 3) { src = Wo; ld = 16;  roff = 0;  coff = 0; }
    else if (f == 4) { src = W1; ld = 32;  roff = 0;  coff = 0; }
    else if (f == 5) { src = W1; ld = 32;  roff = 0;  coff = 16; }
    else if (f == 6) { src = W2; ld = 16;  roff = 0;  coff = 0; }
    else if (f == 7) { src = W2; ld = 16;  roff = 16; coff = 0; }
    else             { src = Wh; ld = 256; roff = 0;  coff = 16 * (f - 8); }
    const uint32_t lo = pk2h(src[(roff + k0 + 0) * ld + coff + c],
                             src[(roff + k0 + 1) * ld + coff + c]);
    const uint32_t hi = pk2h(src[(roff + k0 + 2) * ld + coff + c],
                             src[(roff + k0 + 3) * ld + coff + c]);
    pw[i] = (uint64_t)lo | ((uint64_t)hi << 32);
}

// ---------------------------------------------------------------------------
// Fused transformer: 1 wave = one 16-row tile (2 seq-items) end-to-end.
// All GEMMs on the matrix pipe; softmax reduce = 1 swizzle + 1 bpermute;
// single LDS transpose (X1); head fused so body compute overlaps head
// stores across blocks. 26 MFMA + ~200 VALU per tile.
// ---------------------------------------------------------------------------
__global__ __launch_bounds__(256) void fused_mfma_kernel(
    const int* __restrict__ x,
    const float* __restrict__ te, const float* __restrict__ pe,
    const float* __restrict__ bq, const float* __restrict__ bk,
    const float* __restrict__ bv, const float* __restrict__ bo,
    const float* __restrict__ b1, const float* __restrict__ b2,
    const float* __restrict__ bh,
    const f16x4* __restrict__ pw,
    float* __restrict__ out)
{
    __shared__ float xls[4][320];   // per-wave [16][20] f32 transpose buffer

    const int tid = threadIdx.x;
    const int wv = tid >> 6, l = tid & 63;
    const int g = l >> 4, c = l & 15, k0 = g * 4;

    // fragments (once)
    const f16x4 Fq  = pw[0 * 64 + l], Fk  = pw[1 * 64 + l];
    const f16x4 Fv  = pw[2 * 64 + l], Fo  = pw[3 * 64 + l];
    const f16x4 F1a = pw[4 * 64 + l], F1b = pw[5 * 64 + l];
    const f16x4 F2a = pw[6 * 64 + l], F2b = pw[7 * 64 + l];
    f16x4 Fh[16];
    #pragma unroll
    for (int t = 0; t < 16; ++t) Fh[t] = pw[(8 + t) * 64 + l];

    // biases (once)
    const f32x4 bq4  = *(const f32x4*)(bq + k0);
    const f32x4 bk4  = *(const f32x4*)(bk + k0);
    const f32x4 bv4  = splat4(bv[c]);
    const f32x4 bo4  = splat4(bo[c]);
    const f32x4 b1a4 = *(const f32x4*)(b1 + k0);
    const f32x4 b1b4 = *(const f32x4*)(b1 + 16 + k0);
    const f32x4 b24  = *(const f32x4*)(b2 + k0);
    f32x4 bh4[16];
    #pragma unroll
    for (int t = 0; t < 16; ++t) bh4[t] = splat4(bh[t * 16 + c]);

    // positional rows (once; tile row base is a multiple of 16)
    const f32x4 peA = *(const f32x4*)(pe + (l & 7) * 16 + k0);
    float peD[4];
    #pragma unroll
    for (int j = 0; j < 4; ++j) peD[j] = pe[((k0 + j) & 7) * 16 + c];

    // softmax helpers: valid iff this lane-group's keyrows belong to col c's item
    const bool keep = ((g >> 1) == (c >> 3));
    const int bpaddr = 4 * (32 * (c >> 3) + c);   // lane holding col c's valid pair-sum
    float* myl = xls[wv];
    const f32x4 zero = splat4(0.f);

    for (int tt = 0; tt < TPW; ++tt) {
        const int tile = blockIdx.x * (4 * TPW) + wv * TPW + tt;
        const int r0 = tile * 16;

        // ---- X in A-layout (f16) and D-layout (f32, for residual) ----
        f16x4 Xf;
        {
            const int idxA = x[r0 + c];
            const f32x4 teA = *(const f32x4*)(te + idxA * DIM + k0);
            f32x4 xa = teA + peA;
            Xf = cvt4(xa);
        }
        f32x4 XD;
        #pragma unroll
        for (int j = 0; j < 4; ++j) {
            const int idxD = x[r0 + k0 + j];
            XD[j] = te[idxD * DIM + c] + peD[j];
        }

        // ---- QKV (bias in C-init; 0.25 folded into Q) ----
        f32x4 qa = MFMA(Fq, Xf, bq4);          // Q^T
        f32x4 ka = MFMA(Fk, Xf, bk4);          // K^T
        f32x4 va = MFMA(Xf, Fv, bv4);          // V
        f16x4 Qf, Kf, Vf;
        #pragma unroll
        for (int j = 0; j < 4; ++j) {
            Qf[j] = (_Float16)(qa[j] * 0.25f);
            Kf[j] = (_Float16)ka[j];
            Vf[j] = (_Float16)va[j];
        }

        // ---- S^T = K @ Q^T, masked softmax over keyrows (rows of S^T) ----
        f32x4 s = MFMA(Kf, Qf, zero);
        #pragma unroll
        for (int j = 0; j < 4; ++j) s[j] = keep ? s[j] : -1e30f;
        float m0 = fmaxf(fmaxf(s[0], s[1]), fmaxf(s[2], s[3]));
        m0 = fmaxf(m0, SWZF(m0, 0x401F));            // pair (xor 16)
        const float mx = bperm(bpaddr, m0);          // broadcast valid pair
        f32x4 p;
        #pragma unroll
        for (int j = 0; j < 4; ++j) p[j] = __expf(s[j] - mx);  // masked -> 0
        float s0 = p[0] + p[1] + p[2] + p[3];
        s0 += SWZF(s0, 0x401F);
        const float inv = 1.0f / bperm(bpaddr, s0);
        const f16x4 Pf = cvt4(p);                    // P^T, unnormalized

        // ---- attn^T = V^T @ P^T (post-normalized) ----
        f32x4 att = MFMA(Vf, Pf, zero);
        #pragma unroll
        for (int j = 0; j < 4; ++j) att[j] *= inv;
        const f16x4 Af = cvt4(att);                  // = attn in A-layout

        // ---- X1 = attn @ Wo + bo + X (D-layout f32) ----
        f32x4 x1 = MFMA(Af, Fo, bo4);
        x1 += XD;

        // ---- transpose X1 via LDS (per-wave buffer, no barrier) ----
        #pragma unroll
        for (int j = 0; j < 4; ++j) myl[(k0 + j) * 20 + c] = x1[j];
        const f32x4 x1t = *(const f32x4*)(myl + c * 20 + k0);  // X1 A-map, f32
        const f16x4 X1f = cvt4(x1t);

        // ---- FFN (transposed): H^T = W1^T @ X1^T, X2^T = W2^T @ H^T ----
        f32x4 ha = MFMA(F1a, X1f, b1a4);
        f32x4 hb = MFMA(F1b, X1f, b1b4);
        #pragma unroll
        for (int j = 0; j < 4; ++j) {
            ha[j] = fmaxf(ha[j], 0.f);
            hb[j] = fmaxf(hb[j], 0.f);
        }
        const f16x4 Haf = cvt4(ha), Hbf = cvt4(hb);
        f32x4 x2 = b24 + x1t;                        // residual + b2
        x2 = MFMA(F2a, Haf, x2);
        x2 = MFMA(F2b, Hbf, x2);
        const f16x4 X2f = cvt4(x2);                  // = X2 in A-layout

        // ---- head: logits = X2 @ Wh + bh ----
        float* ob = out + ((size_t)(r0 + k0)) * VOCAB + c;
        #pragma unroll
        for (int t = 0; t < 16; ++t) {
            f32x4 o = MFMA(X2f, Fh[t], bh4[t]);
            #pragma unroll
            for (int j = 0; j < 4; ++j)
                ob[(size_t)j * VOCAB + t * 16] = o[j];
        }
    }
}

// ---------------------------------------------------------------------------
// Fallback (ws too small): single-pass per-row body + per-column head.
// ---------------------------------------------------------------------------
#define ITEMS_PER_BLOCK 32
#define ITEM_STRIDE 136

__global__ __launch_bounds__(256) void fused_fallback_kernel(
    const int* __restrict__ x,
    const float* __restrict__ token_embed,
    const float* __restrict__ pos_embed,
    const float* __restrict__ Wq, const float* __restrict__ bq,
    const float* __restrict__ Wk, const float* __restrict__ bk,
    const float* __restrict__ Wv, const float* __restrict__ bv,
    const float* __restrict__ Wo, const float* __restrict__ bo,
    const float* __restrict__ W1, const float* __restrict__ b1,
    const float* __restrict__ W2, const float* __restrict__ b2,
    const float* __restrict__ Wh, const float* __restrict__ bh,
    float* __restrict__ out)
{
    __shared__ float sK[ITEMS_PER_BLOCK * ITEM_STRIDE];
    __shared__ float sV[ITEMS_PER_BLOCK * ITEM_STRIDE];

    const int tid = threadIdx.x;
    const int i = tid >> 3;
    const int n = tid & 7;
    const int b = blockIdx.x * ITEMS_PER_BLOCK + i;

    float X[DIM];
    {
        const int idx = x[b * SEQ + n];
        const float4* te4 = (const float4*)(token_embed + idx * DIM);
        const float4* pe4 = (const float4*)(pos_embed + n * DIM);
        #pragma unroll
        for (int j = 0; j < 4; ++j) {
            float4 a = te4[j];
            float4 p = pe4[j];
            X[4*j+0] = a.x + p.x; X[4*j+1] = a.y + p.y;
            X[4*j+2] = a.z + p.z; X[4*j+3] = a.w + p.w;
        }
    }

    float Q[DIM], Kr[DIM], Vr[DIM];
    #pragma unroll
    for (int e = 0; e < DIM; ++e) {
        float qq = bq[e], kk = bk[e], vv = bv[e];
        #pragma unroll
        for (int d = 0; d < DIM; ++d) {
            qq += X[d] * Wq[d * DIM + e];
            kk += X[d] * Wk[d * DIM + e];
            vv += X[d] * Wv[d * DIM + e];
        }
        Q[e] = qq; Kr[e] = kk; Vr[e] = vv;
    }
    {
        float* kdst = sK + i * ITEM_STRIDE + n * DIM;
        float* vdst = sV + i * ITEM_STRIDE + n * DIM;
        #pragma unroll
        for (int j = 0; j < 4; ++j) {
            float4 kk, vv;
            kk.x = Kr[4*j+0]; kk.y = Kr[4*j+1]; kk.z = Kr[4*j+2]; kk.w = Kr[4*j+3];
            vv.x = Vr[4*j+0]; vv.y = Vr[4*j+1]; vv.z = Vr[4*j+2]; vv.w = Vr[4*j+3];
            ((float4*)kdst)[j] = kk;
            ((float4*)vdst)[j] = vv;
        }
    }
    __syncthreads();

    float sc[SEQ];
    #pragma unroll
    for (int m = 0; m < SEQ; ++m) {
        const float* kr = sK + i * ITEM_STRIDE + m * DIM;
        float s = 0.f;
        #pragma unroll
        for (int d = 0; d < DIM; ++d) s += Q[d] * kr[d];
        sc[m] = s * 0.25f;
    }
    float mx = sc[0];
    #pragma unroll
    for (int m = 1; m < SEQ; ++m) mx = fmaxf(mx, sc[m]);
    float sum = 0.f;
    #pragma unroll
    for (int m = 0; m < SEQ; ++m) { sc[m] = __expf(sc[m] - mx); sum += sc[m]; }
    const float inv = 1.0f / sum;

    float at[DIM];
    #pragma unroll
    for (int d = 0; d < DIM; ++d) at[d] = 0.f;
    #pragma unroll
    for (int m = 0; m < SEQ; ++m) {
        const float w = sc[m] * inv;
        const float* vr = sV + i * ITEM_STRIDE + m * DIM;
        #pragma unroll
        for (int d = 0; d < DIM; ++d) at[d] += w * vr[d];
    }

    float X1[DIM];
    #pragma unroll
    for (int e = 0; e < DIM; ++e) {
        float o = bo[e];
        #pragma unroll
        for (int d = 0; d < DIM; ++d) o += at[d] * Wo[d * DIM + e];
        X1[e] = X[e] + o;
    }
    float h[FF];
    #pragma unroll
    for (int f = 0; f < FF; ++f) {
        float a = b1[f];
        #pragma unroll
        for (int d = 0; d < DIM; ++d) a += X1[d] * W1[d * FF + f];
        h[f] = fmaxf(a, 0.f);
    }
    float X2[DIM];
    #pragma unroll
    for (int e = 0; e < DIM; ++e) {
        float a = b2[e];
        #pragma unroll
        for (int f = 0; f < FF; ++f) a += h[f] * W2[f * DIM + e];
        X2[e] = X1[e] + a;
    }

    __syncthreads();
    {
        float* xdst = sK + i * ITEM_STRIDE + n * DIM;
        #pragma unroll
        for (int j = 0; j < 4; ++j) {
            float4 xx;
            xx.x = X2[4*j+0]; xx.y = X2[4*j+1]; xx.z = X2[4*j+2]; xx.w = X2[4*j+3];
            ((float4*)xdst)[j] = xx;
        }
    }
    __syncthreads();

    float wh[DIM];
    #pragma unroll
    for (int d = 0; d < DIM; ++d) wh[d] = Wh[d * VOCAB + tid];
    const float bhv = bh[tid];

    const size_t obase = (size_t)blockIdx.x * (ITEMS_PER_BLOCK * SEQ) * VOCAB + tid;
    #pragma unroll 4
    for (int r = 0; r < ITEMS_PER_BLOCK * SEQ; ++r) {
        const float* xr = sK + (r >> 3) * ITEM_STRIDE + (r & 7) * DIM;
        float acc = bhv;
        #pragma unroll
        for (int d = 0; d < DIM; ++d) acc += xr[d] * wh[d];
        out[obase + (size_t)r * VOCAB] = acc;
    }
}

extern "C" void kernel_launch(void* const* d_in, const int* in_sizes, int n_in,
                              void* d_out, int out_size, void* d_ws, size_t ws_size,
                              hipStream_t stream) {
    const int*   x           = (const int*)  d_in[0];
    const float* token_embed = (const float*)d_in[1];
    const float* pos_embed   = (const float*)d_in[2];
    const float* Wq = (const float*)d_in[3];
    const float* bq = (const float*)d_in[4];
    const float* Wk = (const float*)d_in[5];
    const float* bk = (const float*)d_in[6];
    const float* Wv = (const float*)d_in[7];
    const float* bv = (const float*)d_in[8];
    const float* Wo = (const float*)d_in[9];
    const float* bo = (const float*)d_in[10];
    const float* W1 = (const float*)d_in[11];
    const float* b1 = (const float*)d_in[12];
    const float* W2 = (const float*)d_in[13];
    const float* b2 = (const float*)d_in[14];
    const float* Wh = (const float*)d_in[15];
    const float* bh = (const float*)d_in[16];
    float* out = (float*)d_out;

    const int B = in_sizes[0] / SEQ;                 // 32768
    const int nrows = B * SEQ;                       // 262144
    const int ntiles = nrows / 16;                   // 16384
    const size_t ws_needed = (size_t)NFRAG * 64 * 8; // 12 KB

    if (ws_size >= ws_needed) {
        uint64_t* pw = (uint64_t*)d_ws;
        pack_frags_kernel<<<(NFRAG * 64 + 255) / 256, 256, 0, stream>>>(
            Wq, Wk, Wv, Wo, W1, W2, Wh, pw);
        fused_mfma_kernel<<<ntiles / (4 * TPW), 256, 0, stream>>>(
            x, token_embed, pos_embed, bq, bk, bv, bo, b1, b2, bh,
            (const f16x4*)pw, out);
    } else {
        fused_fallback_kernel<<<B / ITEMS_PER_BLOCK, 256, 0, stream>>>(
            x, token_embed, pos_embed, Wq, bq, Wk, bk, Wv, bv, Wo, bo,
            W1, b1, W2, b2, Wh, bh, out);
    }
}

// Round 14
// 54.055 us; speedup vs baseline: 3.6883x; 1.0219x over previous
//
#include <hip/hip_runtime.h>
#include <hip/hip_fp16.h>
#include <stdint.h>

#define SEQ 8
#define DIM 16
#define FF 32
#define VOCAB 256
#define TPW 4      // tiles (16 rows each) per wave
#define NFRAG 24   // 8 body fragments + 16 head fragments

typedef _Float16 f16x4 __attribute__((ext_vector_type(4)));
typedef float f32x4 __attribute__((ext_vector_type(4)));

#define SWZF(val, imm) __int_as_float(__builtin_amdgcn_ds_swizzle(__float_as_int(val), (imm)))
#define MFMA(a, b, c) __builtin_amdgcn_mfma_f32_16x16x16f16((a), (b), (c), 0, 0, 0)

__device__ __forceinline__ uint32_t pk2h(float a, float b) {
    return (uint32_t)__half_as_ushort(__float2half(a))
         | ((uint32_t)__half_as_ushort(__float2half(b)) << 16);
}
__device__ __forceinline__ f32x4 splat4(float s) {
    f32x4 r;
    r[0] = s; r[1] = s; r[2] = s; r[3] = s;
    return r;
}
__device__ __forceinline__ f16x4 cvt4(f32x4 a) {
    f16x4 r;
    r[0] = (_Float16)a[0]; r[1] = (_Float16)a[1];
    r[2] = (_Float16)a[2]; r[3] = (_Float16)a[3];
    return r;
}
__device__ __forceinline__ float bperm(int addr, float v) {
    return __int_as_float(__builtin_amdgcn_ds_bpermute(addr, __float_as_int(v)));
}

// ---------------------------------------------------------------------------
// Pack weights into f16 MFMA fragments. Shared per-lane map (validated R11):
//   frag[l] reg i  <->  M[roff + (l>>4)*4 + i][col(l)]
// Body frags f=0..7 as before. Head frags f=8..23 use a PERMUTED vocab
// mapping: frag t = 4*t1+t0, lane col c -> vocab col 4c + t0 + 64*t1, so the
// head can buffer t0=0..3 and emit contiguous dwordx4 stores (256B/group).
// ---------------------------------------------------------------------------
__global__ __launch_bounds__(256) void pack_frags_kernel(
    const float* __restrict__ Wq, const float* __restrict__ Wk,
    const float* __restrict__ Wv, const float* __restrict__ Wo,
    const float* __restrict__ W1, const float* __restrict__ W2,
    const float* __restrict__ Wh, uint64_t* __restrict__ pw)
{
    const int i = blockIdx.x * 256 + threadIdx.x;
    if (i >= NFRAG * 64) return;
    const int f = i >> 6, l = i & 63;
    const int k0 = (l >> 4) * 4, c = l & 15;
    const float* src; int ld, roff, col;
    if      (f == 0) { src = Wq; ld = 16;  roff = 0;  col = c; }
    else if (f == 1) { src = Wk; ld = 16;  roff = 0;  col = c; }
    else if (f == 2) { src = Wv; ld = 16;  roff = 0;  col = c; }
    else if (f == 3) { src = Wo; ld = 16;  roff = 0;  col = c; }
    else if (f == 4) { src = W1; ld = 32;  roff = 0;  col = c; }
    else if (f == 5) { src = W1; ld = 32;  roff = 0;  col = 16 + c; }
    else if (f == 6) { src = W2; ld = 16;  roff = 0;  col = c; }
    else if (f == 7) { src = W2; ld = 16;  roff = 16; col = c; }
    else {
        const int t = f - 8;
        src = Wh; ld = 256; roff = 0;
        col = 4 * c + (t & 3) + 64 * (t >> 2);
    }
    const uint32_t lo = pk2h(src[(roff + k0 + 0) * ld + col],
                             src[(roff + k0 + 1) * ld + col]);
    const uint32_t hi = pk2h(src[(roff + k0 + 2) * ld + col],
                             src[(roff + k0 + 3) * ld + col]);
    pw[i] = (uint64_t)lo | ((uint64_t)hi << 32);
}

// ---------------------------------------------------------------------------
// Fused transformer: 1 wave = one 16-row tile (2 seq-items) end-to-end.
// All GEMMs on the matrix pipe; softmax reduce = 1 swizzle + 1 bpermute;
// single LDS transpose (X1); head fused with vocab-permuted fragments so
// stores are contiguous dwordx4 (256B per 16-lane group), 16 stores/tile.
// ---------------------------------------------------------------------------
__global__ __launch_bounds__(256) void fused_mfma_kernel(
    const int* __restrict__ x,
    const float* __restrict__ te, const float* __restrict__ pe,
    const float* __restrict__ bq, const float* __restrict__ bk,
    const float* __restrict__ bv, const float* __restrict__ bo,
    const float* __restrict__ b1, const float* __restrict__ b2,
    const float* __restrict__ bh,
    const f16x4* __restrict__ pw,
    float* __restrict__ out)
{
    __shared__ float xls[4][320];   // per-wave [16][20] f32 transpose buffer

    const int tid = threadIdx.x;
    const int wv = tid >> 6, l = tid & 63;
    const int g = l >> 4, c = l & 15, k0 = g * 4;

    // fragments (once)
    const f16x4 Fq  = pw[0 * 64 + l], Fk  = pw[1 * 64 + l];
    const f16x4 Fv  = pw[2 * 64 + l], Fo  = pw[3 * 64 + l];
    const f16x4 F1a = pw[4 * 64 + l], F1b = pw[5 * 64 + l];
    const f16x4 F2a = pw[6 * 64 + l], F2b = pw[7 * 64 + l];
    f16x4 Fh[16];
    #pragma unroll
    for (int t = 0; t < 16; ++t) Fh[t] = pw[(8 + t) * 64 + l];

    // biases (once)
    const f32x4 bq4  = *(const f32x4*)(bq + k0);
    const f32x4 bk4  = *(const f32x4*)(bk + k0);
    const f32x4 bv4  = splat4(bv[c]);
    const f32x4 bo4  = splat4(bo[c]);
    const f32x4 b1a4 = *(const f32x4*)(b1 + k0);
    const f32x4 b1b4 = *(const f32x4*)(b1 + 16 + k0);
    const f32x4 b24  = *(const f32x4*)(b2 + k0);
    float bhv[16];
    #pragma unroll
    for (int t = 0; t < 16; ++t)
        bhv[t] = bh[4 * c + (t & 3) + 64 * (t >> 2)];   // permuted vocab map

    // positional rows (once; tile row base is a multiple of 16)
    const f32x4 peA = *(const f32x4*)(pe + (l & 7) * 16 + k0);
    float peD[4];
    #pragma unroll
    for (int j = 0; j < 4; ++j) peD[j] = pe[((k0 + j) & 7) * 16 + c];

    // softmax helpers: valid iff this lane-group's keyrows belong to col c's item
    const bool keep = ((g >> 1) == (c >> 3));
    const int bpaddr = 4 * (32 * (c >> 3) + c);   // lane holding col c's valid pair-sum
    float* myl = xls[wv];
    const f32x4 zero = splat4(0.f);

    for (int tt = 0; tt < TPW; ++tt) {
        const int tile = blockIdx.x * (4 * TPW) + wv * TPW + tt;
        const int r0 = tile * 16;

        // ---- X in A-layout (f16) and D-layout (f32, for residual) ----
        f16x4 Xf;
        {
            const int idxA = x[r0 + c];
            const f32x4 teA = *(const f32x4*)(te + idxA * DIM + k0);
            f32x4 xa = teA + peA;
            Xf = cvt4(xa);
        }
        f32x4 XD;
        #pragma unroll
        for (int j = 0; j < 4; ++j) {
            const int idxD = x[r0 + k0 + j];
            XD[j] = te[idxD * DIM + c] + peD[j];
        }

        // ---- QKV (bias in C-init; 0.25 folded into Q) ----
        f32x4 qa = MFMA(Fq, Xf, bq4);          // Q^T
        f32x4 ka = MFMA(Fk, Xf, bk4);          // K^T
        f32x4 va = MFMA(Xf, Fv, bv4);          // V
        f16x4 Qf, Kf, Vf;
        #pragma unroll
        for (int j = 0; j < 4; ++j) {
            Qf[j] = (_Float16)(qa[j] * 0.25f);
            Kf[j] = (_Float16)ka[j];
            Vf[j] = (_Float16)va[j];
        }

        // ---- S^T = K @ Q^T, masked softmax over keyrows (rows of S^T) ----
        f32x4 s = MFMA(Kf, Qf, zero);
        #pragma unroll
        for (int j = 0; j < 4; ++j) s[j] = keep ? s[j] : -1e30f;
        float m0 = fmaxf(fmaxf(s[0], s[1]), fmaxf(s[2], s[3]));
        m0 = fmaxf(m0, SWZF(m0, 0x401F));            // pair (xor 16)
        const float mx = bperm(bpaddr, m0);          // broadcast valid pair
        f32x4 p;
        #pragma unroll
        for (int j = 0; j < 4; ++j) p[j] = __expf(s[j] - mx);  // masked -> 0
        float s0 = p[0] + p[1] + p[2] + p[3];
        s0 += SWZF(s0, 0x401F);
        const float inv = 1.0f / bperm(bpaddr, s0);
        const f16x4 Pf = cvt4(p);                    // P^T, unnormalized

        // ---- attn^T = V^T @ P^T (post-normalized) ----
        f32x4 att = MFMA(Vf, Pf, zero);
        #pragma unroll
        for (int j = 0; j < 4; ++j) att[j] *= inv;
        const f16x4 Af = cvt4(att);                  // = attn in A-layout

        // ---- X1 = attn @ Wo + bo + X (D-layout f32) ----
        f32x4 x1 = MFMA(Af, Fo, bo4);
        x1 += XD;

        // ---- transpose X1 via LDS (per-wave buffer, no barrier) ----
        #pragma unroll
        for (int j = 0; j < 4; ++j) myl[(k0 + j) * 20 + c] = x1[j];
        const f32x4 x1t = *(const f32x4*)(myl + c * 20 + k0);  // X1 A-map, f32
        const f16x4 X1f = cvt4(x1t);

        // ---- FFN (transposed): H^T = W1^T @ X1^T, X2^T = W2^T @ H^T ----
        f32x4 ha = MFMA(F1a, X1f, b1a4);
        f32x4 hb = MFMA(F1b, X1f, b1b4);
        #pragma unroll
        for (int j = 0; j < 4; ++j) {
            ha[j] = fmaxf(ha[j], 0.f);
            hb[j] = fmaxf(hb[j], 0.f);
        }
        const f16x4 Haf = cvt4(ha), Hbf = cvt4(hb);
        f32x4 x2 = b24 + x1t;                        // residual + b2
        x2 = MFMA(F2a, Haf, x2);
        x2 = MFMA(F2b, Hbf, x2);
        const f16x4 X2f = cvt4(x2);                  // = X2 in A-layout

        // ---- head: logits = X2 @ Wh + bh, contiguous dwordx4 stores ----
        // frag t=4*t1+t0, lane col c -> vocab col 4c + t0 + 64*t1.
        #pragma unroll
        for (int t1 = 0; t1 < 4; ++t1) {
            f32x4 o0 = MFMA(X2f, Fh[4 * t1 + 0], splat4(bhv[4 * t1 + 0]));
            f32x4 o1 = MFMA(X2f, Fh[4 * t1 + 1], splat4(bhv[4 * t1 + 1]));
            f32x4 o2 = MFMA(X2f, Fh[4 * t1 + 2], splat4(bhv[4 * t1 + 2]));
            f32x4 o3 = MFMA(X2f, Fh[4 * t1 + 3], splat4(bhv[4 * t1 + 3]));
            #pragma unroll
            for (int j = 0; j < 4; ++j) {
                f32x4 st;
                st[0] = o0[j]; st[1] = o1[j]; st[2] = o2[j]; st[3] = o3[j];
                *(f32x4*)(out + (size_t)(r0 + k0 + j) * VOCAB + 64 * t1 + 4 * c) = st;
            }
        }
    }
}

// ---------------------------------------------------------------------------
// Fallback (ws too small): single-pass per-row body + per-column head.
// ---------------------------------------------------------------------------
#define ITEMS_PER_BLOCK 32
#define ITEM_STRIDE 136

__global__ __launch_bounds__(256) void fused_fallback_kernel(
    const int* __restrict__ x,
    const float* __restrict__ token_embed,
    const float* __restrict__ pos_embed,
    const float* __restrict__ Wq, const float* __restrict__ bq,
    const float* __restrict__ Wk, const float* __restrict__ bk,
    const float* __restrict__ Wv, const float* __restrict__ bv,
    const float* __restrict__ Wo, const float* __restrict__ bo,
    const float* __restrict__ W1, const float* __restrict__ b1,
    const float* __restrict__ W2, const float* __restrict__ b2,
    const float* __restrict__ Wh, const float* __restrict__ bh,
    float* __restrict__ out)
{
    __shared__ float sK[ITEMS_PER_BLOCK * ITEM_STRIDE];
    __shared__ float sV[ITEMS_PER_BLOCK * ITEM_STRIDE];

    const int tid = threadIdx.x;
    const int i = tid >> 3;
    const int n = tid & 7;
    const int b = blockIdx.x * ITEMS_PER_BLOCK + i;

    float X[DIM];
    {
        const int idx = x[b * SEQ + n];
        const float4* te4 = (const float4*)(token_embed + idx * DIM);
        const float4* pe4 = (const float4*)(pos_embed + n * DIM);
        #pragma unroll
        for (int j = 0; j < 4; ++j) {
            float4 a = te4[j];
            float4 p = pe4[j];
            X[4*j+0] = a.x + p.x; X[4*j+1] = a.y + p.y;
            X[4*j+2] = a.z + p.z; X[4*j+3] = a.w + p.w;
        }
    }

    float Q[DIM], Kr[DIM], Vr[DIM];
    #pragma unroll
    for (int e = 0; e < DIM; ++e) {
        float qq = bq[e], kk = bk[e], vv = bv[e];
        #pragma unroll
        for (int d = 0; d < DIM; ++d) {
            qq += X[d] * Wq[d * DIM + e];
            kk += X[d] * Wk[d * DIM + e];
            vv += X[d] * Wv[d * DIM + e];
        }
        Q[e] = qq; Kr[e] = kk; Vr[e] = vv;
    }
    {
        float* kdst = sK + i * ITEM_STRIDE + n * DIM;
        float* vdst = sV + i * ITEM_STRIDE + n * DIM;
        #pragma unroll
        for (int j = 0; j < 4; ++j) {
            float4 kk, vv;
            kk.x = Kr[4*j+0]; kk.y = Kr[4*j+1]; kk.z = Kr[4*j+2]; kk.w = Kr[4*j+3];
            vv.x = Vr[4*j+0]; vv.y = Vr[4*j+1]; vv.z = Vr[4*j+2]; vv.w = Vr[4*j+3];
            ((float4*)kdst)[j] = kk;
            ((float4*)vdst)[j] = vv;
        }
    }
    __syncthreads();

    float sc[SEQ];
    #pragma unroll
    for (int m = 0; m < SEQ; ++m) {
        const float* kr = sK + i * ITEM_STRIDE + m * DIM;
        float s = 0.f;
        #pragma unroll
        for (int d = 0; d < DIM; ++d) s += Q[d] * kr[d];
        sc[m] = s * 0.25f;
    }
    float mx = sc[0];
    #pragma unroll
    for (int m = 1; m < SEQ; ++m) mx = fmaxf(mx, sc[m]);
    float sum = 0.f;
    #pragma unroll
    for (int m = 0; m < SEQ; ++m) { sc[m] = __expf(sc[m] - mx); sum += sc[m]; }
    const float inv = 1.0f / sum;

    float at[DIM];
    #pragma unroll
    for (int d = 0; d < DIM; ++d) at[d] = 0.f;
    #pragma unroll
    for (int m = 0; m < SEQ; ++m) {
        const float w = sc[m] * inv;
        const float* vr = sV + i * ITEM_STRIDE + m * DIM;
        #pragma unroll
        for (int d = 0; d < DIM; ++d) at[d] += w * vr[d];
    }

    float X1[DIM];
    #pragma unroll
    for (int e = 0; e < DIM; ++e) {
        float o = bo[e];
        #pragma unroll
        for (int d = 0; d < DIM; ++d) o += at[d] * Wo[d * DIM + e];
        X1[e] = X[e] + o;
    }
    float h[FF];
    #pragma unroll
    for (int f = 0; f < FF; ++f) {
        float a = b1[f];
        #pragma unroll
        for (int d = 0; d < DIM; ++d) a += X1[d] * W1[d * FF + f];
        h[f] = fmaxf(a, 0.f);
    }
    float X2[DIM];
    #pragma unroll
    for (int e = 0; e < DIM; ++e) {
        float a = b2[e];
        #pragma unroll
        for (int f = 0; f < FF; ++f) a += h[f] * W2[f * DIM + e];
        X2[e] = X1[e] + a;
    }

    __syncthreads();
    {
        float* xdst = sK + i * ITEM_STRIDE + n * DIM;
        #pragma unroll
        for (int j = 0; j < 4; ++j) {
            float4 xx;
            xx.x = X2[4*j+0]; xx.y = X2[4*j+1]; xx.z = X2[4*j+2]; xx.w = X2[4*j+3];
            ((float4*)xdst)[j] = xx;
        }
    }
    __syncthreads();

    float wh[DIM];
    #pragma unroll
    for (int d = 0; d < DIM; ++d) wh[d] = Wh[d * VOCAB + tid];
    const float bhv = bh[tid];

    const size_t obase = (size_t)blockIdx.x * (ITEMS_PER_BLOCK * SEQ) * VOCAB + tid;
    #pragma unroll 4
    for (int r = 0; r < ITEMS_PER_BLOCK * SEQ; ++r) {
        const float* xr = sK + (r >> 3) * ITEM_STRIDE + (r & 7) * DIM;
        float acc = bhv;
        #pragma unroll
        for (int d = 0; d < DIM; ++d) acc += xr[d] * wh[d];
        out[obase + (size_t)r * VOCAB] = acc;
    }
}

extern "C" void kernel_launch(void* const* d_in, const int* in_sizes, int n_in,
                              void* d_out, int out_size, void* d_ws, size_t ws_size,
                              hipStream_t stream) {
    const int*   x           = (const int*)  d_in[0];
    const float* token_embed = (const float*)d_in[1];
    const float* pos_embed   = (const float*)d_in[2];
    const float* Wq = (const float*)d_in[3];
    const float* bq = (const float*)d_in[4];
    const float* Wk = (const float*)d_in[5];
    const float* bk = (const float*)d_in[6];
    const float* Wv = (const float*)d_in[7];
    const float* bv = (const float*)d_in[8];
    const float* Wo = (const float*)d_in[9];
    const float* bo = (const float*)d_in[10];
    const float* W1 = (const float*)d_in[11];
    const float* b1 = (const float*)d_in[12];
    const float* W2 = (const float*)d_in[13];
    const float* b2 = (const float*)d_in[14];
    const float* Wh = (const float*)d_in[15];
    const float* bh = (const float*)d_in[16];
    float* out = (float*)d_out;

    const int B = in_sizes[0] / SEQ;                 // 32768
    const int nrows = B * SEQ;                       // 262144
    const int ntiles = nrows / 16;                   // 16384
    const size_t ws_needed = (size_t)NFRAG * 64 * 8; // 12 KB

    if (ws_size >= ws_needed) {
        uint64_t* pw = (uint64_t*)d_ws;
        pack_frags_kernel<<<(NFRAG * 64 + 255) / 256, 256, 0, stream>>>(
            Wq, Wk, Wv, Wo, W1, W2, Wh, pw);
        fused_mfma_kernel<<<ntiles / (4 * TPW), 256, 0, stream>>>(
            x, token_embed, pos_embed, bq, bk, bv, bo, b1, b2, bh,
            (const f16x4*)pw, out);
    } else {
        fused_fallback_kernel<<<B / ITEMS_PER_BLOCK, 256, 0, stream>>>(
            x, token_embed, pos_embed, Wq, bq, Wk, bk, Wv, bv, Wo, bo,
            W1, b1, W2, b2, Wh, bh, out);
    }
}